// Round 12
// baseline (567.057 us; speedup 1.0000x reference)
//
#include <hip/hip_runtime.h>

#define NTOK 8192
#define IDIM 1024
#define HDIM 4096
#define ODIM 1024
#define NEXP 8
#define ROWCAP 18432          // NTOK*2 + NEXP*256
#define MBLK 72               // ROWCAP / 256
#define GATE_BLOCKS 512

typedef unsigned short u16;
typedef __attribute__((ext_vector_type(8))) __bf16 bf16x8;
typedef __attribute__((ext_vector_type(8))) short short8;
typedef __attribute__((ext_vector_type(4))) float f32x4;
typedef __attribute__((ext_vector_type(4))) unsigned short u16x4;
typedef __attribute__((ext_vector_type(8))) unsigned short u16x8;

__device__ __forceinline__ u16 f2bf(float f) {
  union { float f; unsigned u; } c; c.f = f;
  unsigned u = c.u;
  return (u16)((u + 0x7fffu + ((u >> 16) & 1u)) >> 16);
}
__device__ __forceinline__ float bf2f(u16 h) {
  union { unsigned u; float f; } c; c.u = ((unsigned)h) << 16;
  return c.f;
}
__device__ __forceinline__ void gload16(const void* g, void* l) {
  __builtin_amdgcn_global_load_lds((const __attribute__((address_space(1))) unsigned*)g,
                                   (__attribute__((address_space(3))) unsigned*)l, 16, 0, 0);
}

#define BARR __builtin_amdgcn_s_barrier()
#define LGKM0 asm volatile("s_waitcnt lgkmcnt(0)" ::: "memory")
#define VMW4 asm volatile("s_waitcnt vmcnt(4)" ::: "memory")
#define VMW8 asm volatile("s_waitcnt vmcnt(8)" ::: "memory")
#define VMW0 asm volatile("s_waitcnt vmcnt(0)" ::: "memory")
#define CFENCE asm volatile("" ::: "memory")

#define QUAD(AF, BF, MB, NBQ)                                                   \
  _Pragma("unroll") for (int kk = 0; kk < 2; ++kk)                              \
  _Pragma("unroll") for (int f = 0; f < 4; ++f)                                 \
  _Pragma("unroll") for (int n = 0; n < 2; ++n)                                 \
    acc[(MB) + f][(NBQ) + n] = __builtin_amdgcn_mfma_f32_16x16x32_bf16(         \
        AF[f][kk], BF[n][kk], acc[(MB) + f][(NBQ) + n], 0, 0, 0);

// ============ fast transpose-convert: 128x128 tiles, XOR-swizzled LDS, 32KB ============
__global__ __launch_bounds__(256) void transpose_convert_kernel(
    const float* __restrict__ w1, const float* __restrict__ w2,
    u16* __restrict__ w1t, u16* __restrict__ w2t) {
  __shared__ __align__(16) unsigned char ldsb[32768];
  int bid = blockIdx.x;
  const float* in; u16* outp; int R, C, r0, c0;
  if (bid < 2048) {
    int e = bid >> 8, t = bid & 255;
    in = w1 + (size_t)e * IDIM * HDIM; outp = w1t + (size_t)e * IDIM * HDIM;
    R = IDIM; C = HDIM;
    r0 = (t >> 5) * 128; c0 = (t & 31) * 128;
  } else {
    int b2 = bid - 2048;
    int e = b2 >> 8, t = b2 & 255;
    in = w2 + (size_t)e * HDIM * ODIM; outp = w2t + (size_t)e * HDIM * ODIM;
    R = HDIM; C = ODIM;
    r0 = (t >> 3) * 128; c0 = (t & 7) * 128;
  }
  int tid = threadIdx.x;
  int rr = tid >> 5, cc = (tid & 31) * 4;
  #pragma unroll
  for (int it = 0; it < 16; ++it) {
    int r = it * 8 + rr;
    f32x4 v = *(const f32x4*)(in + (size_t)(r0 + r) * C + c0 + cc);
    u16x4 o;
    #pragma unroll
    for (int j = 0; j < 4; ++j) o[j] = f2bf(v[j]);
    unsigned a = ((unsigned)(r * 256 + cc * 2)) ^ ((((unsigned)r >> 3) & 7u) << 4);
    *(u16x4*)(ldsb + a) = o;
  }
  __syncthreads();
  int rc = tid & 15, cg = tid >> 4;
  #pragma unroll
  for (int i = 0; i < 8; ++i) {
    int c = cg + i * 16;
    u16x8 o;
    #pragma unroll
    for (int k = 0; k < 8; ++k) {
      int r = rc * 8 + k;
      unsigned a = ((unsigned)(r * 256 + c * 2)) ^ ((((unsigned)r >> 3) & 7u) << 4);
      o[k] = *(const u16*)(ldsb + a);
    }
    *(u16x8*)(outp + (size_t)(c0 + c) * R + r0 + rc * 8) = o;
  }
}

// ---------------- gating: atomic-free; vectorized LDS dot (wgs3[e][i4][j]) ----------------
__global__ __launch_bounds__(256) void gating_kernel(
    const float* __restrict__ x, const float* __restrict__ wg, const float* __restrict__ bg,
    float* __restrict__ combine, float* __restrict__ imp_partial,
    int* __restrict__ sel, u16* __restrict__ xb) {
  __shared__ float wgs3[NEXP * IDIM];   // [e][i4][j]: e*1024 + i4*4 + j
  __shared__ float impw[4][NEXP];
  int tid = threadIdx.x;
  for (int d = tid; d < IDIM * NEXP; d += 256)
    wgs3[d] = wg[(d & 1023) * 8 + (d >> 10)];
  __syncthreads();
  int wave = tid >> 6, lane = tid & 63;
  float impacc[NEXP];
  #pragma unroll
  for (int e = 0; e < NEXP; ++e) impacc[e] = 0.f;

  #pragma unroll
  for (int it = 0; it < 4; ++it) {
    int t = blockIdx.x * 16 + wave * 4 + it;
    const float* xr = x + (size_t)t * IDIM;
    u16* xbw = xb + (size_t)t * IDIM;
    float s[NEXP];
    #pragma unroll
    for (int e = 0; e < NEXP; ++e) s[e] = 0.f;
    #pragma unroll
    for (int ii = 0; ii < 4; ++ii) {
      int base = ii * 256 + lane * 4;
      f32x4 xv = *(const f32x4*)(xr + base);
      u16x4 o;
      #pragma unroll
      for (int j = 0; j < 4; ++j) o[j] = f2bf(xv[j]);
      *(u16x4*)(xbw + base) = o;
      const float* wp = wgs3 + (size_t)(ii * 64 + lane) * 4;
      #pragma unroll
      for (int e = 0; e < NEXP; ++e) {
        f32x4 wv = *(const f32x4*)(wp + e * 1024);
        s[e] = fmaf(xv[0], wv[0], s[e]);
        s[e] = fmaf(xv[1], wv[1], s[e]);
        s[e] = fmaf(xv[2], wv[2], s[e]);
        s[e] = fmaf(xv[3], wv[3], s[e]);
      }
    }
    #pragma unroll
    for (int e = 0; e < NEXP; ++e) {
      #pragma unroll
      for (int off = 32; off; off >>= 1) s[e] += __shfl_xor(s[e], off);
    }
    if (lane == 0) {
      #pragma unroll
      for (int e = 0; e < NEXP; ++e) s[e] += bg[e];
      int i1 = 0; float v1 = s[0];
      #pragma unroll
      for (int e = 1; e < NEXP; ++e) if (s[e] > v1) { v1 = s[e]; i1 = e; }
      int i2 = -1; float v2 = -1e30f;
      #pragma unroll
      for (int e = 0; e < NEXP; ++e) if (e != i1 && s[e] > v2) { v2 = s[e]; i2 = e; }
      float p[NEXP], sum = 0.f;
      #pragma unroll
      for (int e = 0; e < NEXP; ++e) { p[e] = expf(s[e] - v1); sum += p[e]; }
      float inv = 1.f / sum;
      #pragma unroll
      for (int e = 0; e < NEXP; ++e) { p[e] *= inv; impacc[e] += p[e]; }
      float c1 = 1.f / (1.f + expf(v2 - v1));
      float c2 = 1.f - c1;
      #pragma unroll
      for (int e = 0; e < NEXP; ++e) combine[(size_t)t * NEXP + e] = 0.f;
      combine[(size_t)t * NEXP + i1] = c1;
      combine[(size_t)t * NEXP + i2] = c2;
      sel[t] = i1 | (i2 << 4);
    }
  }
  if (lane == 0) {
    #pragma unroll
    for (int e = 0; e < NEXP; ++e) impw[wave][e] = impacc[e];
  }
  __syncthreads();
  if (tid == 0) {
    #pragma unroll
    for (int e = 0; e < NEXP; ++e)
      imp_partial[blockIdx.x * NEXP + e] = impw[0][e] + impw[1][e] + impw[2][e] + impw[3][e];
  }
}

// ---------------- compact: 8 blocks (one per expert); token-ordered, deterministic ----------------
__global__ __launch_bounds__(256) void compact_kernel(
    const int* __restrict__ sel, int* __restrict__ tokenlist,
    int* __restrict__ cnt, int* __restrict__ pos) {
  __shared__ int warpsum[4];
  int e = blockIdx.x;
  int tid = threadIdx.x, lane = tid & 63, wave = tid >> 6;
  int base = 0;
  for (int chunk = 0; chunk < NTOK; chunk += 256) {
    int t = chunk + tid;
    int s = sel[t];
    int i1 = s & 15, i2 = s >> 4;
    bool m2 = (i2 == e);
    bool m = (i1 == e) || m2;
    unsigned long long bal = __ballot(m);
    int rank = __popcll(bal & ((1ull << lane) - 1ull));
    if (lane == 0) warpsum[wave] = __popcll(bal);
    __syncthreads();
    int woff = 0;
    #pragma unroll
    for (int w = 0; w < 4; ++w) if (w < wave) woff += warpsum[w];
    int total = warpsum[0] + warpsum[1] + warpsum[2] + warpsum[3];
    if (m) {
      int slot = base + woff + rank;
      tokenlist[e * NTOK + slot] = t;
      pos[t * 2 + (m2 ? 1 : 0)] = (e << 16) | slot;
    }
    base += total;
    __syncthreads();
  }
  if (tid == 0) cnt[e] = base;
}

// ---------------- offsets (pad to 256) + aux loss ----------------
__global__ __launch_bounds__(64) void offsets_aux_kernel(
    const int* __restrict__ cnt, const float* __restrict__ imp_partial,
    int* __restrict__ offsets, float* __restrict__ aux_out) {
  __shared__ float imp[NEXP];
  int tid = threadIdx.x;
  if (tid < NEXP) {
    float v = 0.f;
    for (int b = 0; b < GATE_BLOCKS; ++b) v += imp_partial[b * NEXP + tid];
    imp[tid] = v;
  }
  __syncthreads();
  if (tid == 0) {
    int off = 0;
    for (int e = 0; e < NEXP; ++e) { offsets[e] = off; off += (cnt[e] + 255) & ~255; }
    offsets[NEXP] = off;
    double im = 0.0;
    for (int e = 0; e < NEXP; ++e) im += imp[e];
    im /= NEXP;
    double iv = 0.0;
    for (int e = 0; e < NEXP; ++e) { double d = (double)imp[e] - im; iv += d * d; }
    iv /= (NEXP - 1);
    double il = sqrt(iv) / (im + 1e-6); il = il * il;
    double lm = 0.0;
    for (int e = 0; e < NEXP; ++e) lm += cnt[e];
    lm /= (double)NEXP * NTOK;
    double lv = 0.0;
    for (int e = 0; e < NEXP; ++e) { double d = (double)cnt[e] / NTOK - lm; lv += d * d; }
    lv /= (NEXP - 1);
    double ll = sqrt(lv) / (lm + 1e-6); ll = ll * ll;
    aux_out[0] = (float)(il + ll);
  }
}

// ============ GEMM1: 8-wave, 1-barrier/phase schedule (R8-verified, unchanged) ============
__global__ __launch_bounds__(512, 2) void gemm1_kernel(
    const u16* __restrict__ xb, const u16* __restrict__ w1t, const float* __restrict__ b1,
    const int* __restrict__ tokenlist, const int* __restrict__ cnt,
    const int* __restrict__ offsets, u16* __restrict__ Hbuf) {
  __shared__ __align__(64) unsigned char sm[139264];
  const int NB = HDIM / 256;       // 16
  const int TT = IDIM / 64;        // 16
  int nwg = NB * MBLK;
  int flat = blockIdx.y * NB + blockIdx.x;
  int q = nwg >> 3;
  int swzb = (flat & 7) * q + (flat >> 3);
  int mb = swzb / NB, cb = swzb % NB;
  int grb = mb * 256;
  if (grb >= offsets[NEXP]) return;
  int e = 0;
  #pragma unroll
  for (int k = 0; k < NEXP - 1; ++k) if (grb >= offsets[k + 1]) e = k + 1;
  int lr0 = grb - offsets[e];
  int cnt_e = cnt[e];
  int tid = threadIdx.x, lane = tid & 63, wave = tid >> 6;
  int wr = wave >> 2, wc = wave & 3;

  const int* tl = tokenlist + e * NTOK;
  int colel = (((tid & 7) ^ ((tid >> 3) & 7)) << 3);
  const u16* pA[4]; const u16* pB[4];
  #pragma unroll
  for (int h = 0; h < 2; ++h)
    #pragma unroll
    for (int j = 0; j < 2; ++j) {
      int rowT = h * 128 + j * 64 + (tid >> 3);
      int tok = tl[min(lr0 + rowT, cnt_e - 1)];
      pA[h * 2 + j] = xb + (size_t)tok * IDIM + colel;
      pB[h * 2 + j] = w1t + ((size_t)e * HDIM + cb * 256 + rowT) * IDIM + colel;
    }
  unsigned ldsw = wave * 1024;

  #define STAGE_A(T, H) { unsigned d = (((T) & 1) << 16) + (H) * 16384 + ldsw; \
      gload16(pA[(H)*2+0] + (T)*64, sm + d); gload16(pA[(H)*2+1] + (T)*64, sm + d + 8192); }
  #define STAGE_B(T, H) { unsigned d = (((T) & 1) << 16) + 32768 + (H) * 16384 + ldsw; \
      gload16(pB[(H)*2+0] + (T)*64, sm + d); gload16(pB[(H)*2+1] + (T)*64, sm + d + 8192); }

  int rA = lane & 15;
  int swz = (((lane >> 4) ^ (lane & 7)) << 4);
  int aOff = wr * 16384 + rA * 128 + swz;
  int bOff = 32768 + wc * 8192 + rA * 128 + swz;

  f32x4 acc[8][4];
  #pragma unroll
  for (int m = 0; m < 8; ++m)
    #pragma unroll
    for (int n = 0; n < 4; ++n) acc[m][n] = (f32x4){0.f, 0.f, 0.f, 0.f};
  bf16x8 af[4][2], bf0[2][2], bf1[2][2];

  STAGE_A(0, 0); STAGE_A(0, 1); STAGE_B(0, 0); STAGE_B(0, 1);
  CFENCE;
  STAGE_B(1, 0); STAGE_B(1, 1);
  VMW4; BARR;

  for (int t = 0; t < TT; ++t) {
    int bufb = (t & 1) << 16;
    #pragma unroll
    for (int f = 0; f < 4; ++f) {
      int o = bufb + aOff + f * 2048;
      af[f][0] = *(const bf16x8*)(sm + o);
      af[f][1] = *(const bf16x8*)(sm + (o ^ 64));
    }
    #pragma unroll
    for (int n = 0; n < 2; ++n) {
      int o = bufb + bOff + n * 2048;
      bf0[n][0] = *(const bf16x8*)(sm + o);
      bf0[n][1] = *(const bf16x8*)(sm + (o ^ 64));
    }
    if (t + 1 < TT) STAGE_A(t + 1, 0);
    BARR; LGKM0;
    __builtin_amdgcn_s_setprio(1);
    QUAD(af, bf0, 0, 0);
    __builtin_amdgcn_s_setprio(0);
    #pragma unroll
    for (int n = 0; n < 2; ++n) {
      int o = bufb + bOff + 4096 + n * 2048;
      bf1[n][0] = *(const bf16x8*)(sm + o);
      bf1[n][1] = *(const bf16x8*)(sm + (o ^ 64));
    }
    if (t + 1 < TT) STAGE_A(t + 1, 1);
    BARR; LGKM0;
    __builtin_amdgcn_s_setprio(1);
    QUAD(af, bf1, 0, 2);
    __builtin_amdgcn_s_setprio(0);
    #pragma unroll
    for (int f = 0; f < 4; ++f) {
      int o = bufb + aOff + 8192 + f * 2048;
      af[f][0] = *(const bf16x8*)(sm + o);
      af[f][1] = *(const bf16x8*)(sm + (o ^ 64));
    }
    BARR; LGKM0;
    __builtin_amdgcn_s_setprio(1);
    QUAD(af, bf1, 4, 2);
    __builtin_amdgcn_s_setprio(0);
    if (t + 2 < TT) { STAGE_B(t + 2, 0); STAGE_B(t + 2, 1); }
    __builtin_amdgcn_s_setprio(1);
    QUAD(af, bf0, 4, 0);
    __builtin_amdgcn_s_setprio(0);
    if (t + 2 < TT) { VMW4; } else { VMW0; }
    BARR;
  }

  #pragma unroll
  for (int n = 0; n < 4; ++n) {
    int colb = (wc * 64 + n * 16 + (lane & 15)) * 2;
    float bias = b1[e * HDIM + cb * 256 + wc * 64 + n * 16 + (lane & 15)];
    #pragma unroll
    for (int m = 0; m < 8; ++m) {
      int row = wr * 128 + m * 16 + (lane >> 4) * 4;
      #pragma unroll
      for (int j = 0; j < 4; ++j)
        *(u16*)(sm + (row + j) * 544 + colb) = f2bf(acc[m][n][j] + bias);
    }
  }
  BARR;
  #pragma unroll
  for (int p = 0; p < 16; ++p) {
    int cidx = p * 512 + tid;
    int row = cidx >> 5, cch = cidx & 31;
    u16x8 v = *(const u16x8*)(sm + row * 544 + cch * 16);
    *(u16x8*)(Hbuf + (size_t)(grb + row) * HDIM + cb * 256 + cch * 8) = v;
  }
  #undef STAGE_A
  #undef STAGE_B
}

// ============ GEMM2: 4-wave, 128x128 per wave (LDS-traffic -33%), split-K=2 ============
__global__ __launch_bounds__(256, 1) void gemm2_kernel(
    const u16* __restrict__ Hbuf, const u16* __restrict__ w2t, const float* __restrict__ b2,
    const int* __restrict__ tokenlist, const int* __restrict__ cnt,
    const int* __restrict__ offsets, const float* __restrict__ combine,
    u16* __restrict__ Gout) {
  __shared__ __align__(64) unsigned char sm[139264];
  const int NB = ODIM / 256;       // 4
  const int TT = (HDIM / 2) / 64;  // 32 per split
  int nwg = NB * MBLK;
  int flat = blockIdx.y * NB + blockIdx.x;
  int q = nwg >> 3;
  int swzb = (flat & 7) * q + (flat >> 3);
  int mb = swzb / NB, cb = swzb % NB;
  int ks = blockIdx.z;
  int grb = mb * 256;
  if (grb >= offsets[NEXP]) return;
  int e = 0;
  #pragma unroll
  for (int k = 0; k < NEXP - 1; ++k) if (grb >= offsets[k + 1]) e = k + 1;
  int lr0 = grb - offsets[e];
  int cnt_e = cnt[e];
  int tid = threadIdx.x, lane = tid & 63, wave = tid >> 6;  // 4 waves
  int wr = wave >> 1, wc = wave & 1;                        // 2M x 2N quadrants
  size_t ksOff = (size_t)ks * (HDIM / 2);
  u16* Gk = Gout + (size_t)ks * ROWCAP * ODIM;

  int colel = (((tid & 7) ^ ((tid >> 3) & 7)) << 3);
  // base pointers: per-thread row (tid>>3) + pre-swizzled col chunk
  const u16* pAb = Hbuf + (size_t)(grb + (tid >> 3)) * HDIM + ksOff + colel;
  const u16* pBb = w2t + ((size_t)e * ODIM + cb * 256 + (tid >> 3)) * HDIM + ksOff + colel;

  // STAGE: half-tile H (128 rows) = 4 gloads (j=0..3, 32-row groups)
  #define STAGE_A(T, H) { unsigned d = (((T) & 1) << 16) + (H) * 16384 + wave * 1024;      \
      gload16(pAb + (size_t)((H) * 128 + 0)  * HDIM + (T) * 64, sm + d + 0);               \
      gload16(pAb + (size_t)((H) * 128 + 32) * HDIM + (T) * 64, sm + d + 4096);            \
      gload16(pAb + (size_t)((H) * 128 + 64) * HDIM + (T) * 64, sm + d + 8192);            \
      gload16(pAb + (size_t)((H) * 128 + 96) * HDIM + (T) * 64, sm + d + 12288); }
  #define STAGE_B(T, H) { unsigned d = (((T) & 1) << 16) + 32768 + (H) * 16384 + wave * 1024; \
      gload16(pBb + (size_t)((H) * 128 + 0)  * HDIM + (T) * 64, sm + d + 0);               \
      gload16(pBb + (size_t)((H) * 128 + 32) * HDIM + (T) * 64, sm + d + 4096);            \
      gload16(pBb + (size_t)((H) * 128 + 64) * HDIM + (T) * 64, sm + d + 8192);            \
      gload16(pBb + (size_t)((H) * 128 + 96) * HDIM + (T) * 64, sm + d + 12288); }

  int rA = lane & 15;
  int swz = (((lane >> 4) ^ (lane & 7)) << 4);
  int aOff = wr * 16384 + rA * 128 + swz;             // wave's 128-row A strip
  int bOff = 32768 + wc * 16384 + rA * 128 + swz;     // wave's 128-col B strip

  f32x4 acc[8][8];
  #pragma unroll
  for (int m = 0; m < 8; ++m)
    #pragma unroll
    for (int n = 0; n < 8; ++n) acc[m][n] = (f32x4){0.f, 0.f, 0.f, 0.f};
  bf16x8 af[8][2], bf[4][2];

  // prologue: A(0) 8 ops, B(0) 8 ops, B(1) 8 ops; VMW8 keeps B(1) in flight
  STAGE_A(0, 0); STAGE_A(0, 1); STAGE_B(0, 0); STAGE_B(0, 1);
  CFENCE;
  STAGE_B(1, 0); STAGE_B(1, 1);
  VMW8; BARR;

  for (int t = 0; t < TT; ++t) {
    int bufb = (t & 1) << 16;
    // P1: read af-lo (8) + bf-lo (8); stage A(t+1)H0; MFMA m0-3 x n0-3
    #pragma unroll
    for (int f = 0; f < 4; ++f) {
      int o = bufb + aOff + f * 2048;
      af[f][0] = *(const bf16x8*)(sm + o);
      af[f][1] = *(const bf16x8*)(sm + (o ^ 64));
    }
    #pragma unroll
    for (int n = 0; n < 4; ++n) {
      int o = bufb + bOff + n * 2048;
      bf[n][0] = *(const bf16x8*)(sm + o);
      bf[n][1] = *(const bf16x8*)(sm + (o ^ 64));
    }
    if (t + 1 < TT) STAGE_A(t + 1, 0);
    BARR; LGKM0;
    __builtin_amdgcn_s_setprio(1);
    QUAD(af, bf, 0, 0);
    QUAD(af, (bf + 2), 0, 2);
    __builtin_amdgcn_s_setprio(0);
    // P2: read af-hi (8); stage A(t+1)H1; MFMA m4-7 x n0-3
    #pragma unroll
    for (int f = 0; f < 4; ++f) {
      int o = bufb + aOff + 8192 + f * 2048;
      af[4 + f][0] = *(const bf16x8*)(sm + o);
      af[4 + f][1] = *(const bf16x8*)(sm + (o ^ 64));
    }
    if (t + 1 < TT) STAGE_A(t + 1, 1);
    BARR; LGKM0;
    __builtin_amdgcn_s_setprio(1);
    QUAD((af + 4), bf, 4, 0);
    QUAD((af + 4), (bf + 2), 4, 2);
    __builtin_amdgcn_s_setprio(0);
    // P3: read bf-hi (8, reuse bf regs); MFMA m4-7 x n4-7
    #pragma unroll
    for (int n = 0; n < 4; ++n) {
      int o = bufb + bOff + 8192 + n * 2048;
      bf[n][0] = *(const bf16x8*)(sm + o);
      bf[n][1] = *(const bf16x8*)(sm + (o ^ 64));
    }
    BARR; LGKM0;
    __builtin_amdgcn_s_setprio(1);
    QUAD((af + 4), bf, 4, 4);
    QUAD((af + 4), (bf + 2), 4, 6);
    __builtin_amdgcn_s_setprio(0);
    // P4: no reads; stage B(t+2) both halves; MFMA m0-3 x n4-7; counted vmcnt
    if (t + 2 < TT) { STAGE_B(t + 2, 0); STAGE_B(t + 2, 1); }
    __builtin_amdgcn_s_setprio(1);
    QUAD(af, bf, 0, 4);
    QUAD(af, (bf + 2), 0, 6);
    __builtin_amdgcn_s_setprio(0);
    if (t + 2 < TT) { VMW8; } else { VMW0; }
    BARR;
  }

  // epilogue: weighted dense bf16, LDS roundtrip (544B/row), coalesced stores
  const int* tl = tokenlist + e * NTOK;
  float bias_n[8];
  #pragma unroll
  for (int n = 0; n < 8; ++n)
    bias_n[n] = (ks == 0) ? b2[e * ODIM + cb * 256 + wc * 128 + n * 16 + (lane & 15)] : 0.f;
  #pragma unroll
  for (int m = 0; m < 8; ++m) {
    #pragma unroll
    for (int j = 0; j < 4; ++j) {
      int rr = wr * 128 + m * 16 + (lane >> 4) * 4 + j;
      int tok = tl[min(lr0 + rr, cnt_e - 1)];
      float c = combine[(size_t)tok * NEXP + e];
      #pragma unroll
      for (int n = 0; n < 8; ++n)
        *(u16*)(sm + rr * 544 + (wc * 128 + n * 16 + (lane & 15)) * 2) =
            f2bf(c * (acc[m][n][j] + bias_n[n]));
    }
  }
  BARR;
  #pragma unroll
  for (int p = 0; p < 32; ++p) {
    int cidx = p * 256 + tid;
    int row = cidx >> 5, cch = cidx & 31;
    u16x8 v = *(const u16x8*)(sm + row * 544 + cch * 16);
    *(u16x8*)(Gk + (size_t)(grb + row) * ODIM + cb * 256 + cch * 8) = v;
  }
  #undef STAGE_A
  #undef STAGE_B
}

// ---------------- LN + exact GELU in place ----------------
__global__ __launch_bounds__(256) void ln_gelu_kernel(
    u16* __restrict__ Hbuf, const float* __restrict__ g, const float* __restrict__ b,
    const int* __restrict__ offsets) {
  int r = blockIdx.x;
  if (r >= offsets[NEXP]) return;
  int e = 0;
  #pragma unroll
  for (int k = 0; k < NEXP - 1; ++k) if (r >= offsets[k + 1]) e = k + 1;
  u16* row = Hbuf + (size_t)r * HDIM;
  const float* ge = g + e * HDIM;
  const float* be = b + e * HDIM;
  int tid = threadIdx.x;
  float s = 0.f, ss = 0.f;
  short8 v[2];
  #pragma unroll
  for (int it = 0; it < 2; ++it) {
    v[it] = *(const short8*)(row + (tid + it * 256) * 8);
    #pragma unroll
    for (int j = 0; j < 8; ++j) { float f = bf2f((u16)v[it][j]); s += f; ss += f * f; }
  }
  #pragma unroll
  for (int off = 32; off; off >>= 1) { s += __shfl_xor(s, off); ss += __shfl_xor(ss, off); }
  __shared__ float rs[4], rss[4];
  int wave = tid >> 6, lane = tid & 63;
  if (lane == 0) { rs[wave] = s; rss[wave] = ss; }
  __syncthreads();
  float S = rs[0] + rs[1] + rs[2] + rs[3];
  float SS = rss[0] + rss[1] + rss[2] + rss[3];
  float mean = S * (1.f / HDIM);
  float var = SS * (1.f / HDIM) - mean * mean;
  float rstd = rsqrtf(var + 1e-5f);
  #pragma unroll
  for (int it = 0; it < 2; ++it) {
    int base = (tid + it * 256) * 8;
    f32x4 g0 = *(const f32x4*)(ge + base);
    f32x4 g1 = *(const f32x4*)(ge + base + 4);
    f32x4 b0 = *(const f32x4*)(be + base);
    f32x4 b1v = *(const f32x4*)(be + base + 4);
    u16x8 o;
    #pragma unroll
    for (int j = 0; j < 8; ++j) {
      float f = bf2f((u16)v[it][j]);
      float gg = j < 4 ? g0[j & 3] : g1[j & 3];
      float bb = j < 4 ? b0[j & 3] : b1v[j & 3];
      float y = (f - mean) * rstd * gg + bb;
      float gel = 0.5f * y * (1.f + erff(y * 0.70710678118654752f));
      o[j] = f2bf(gel);
    }
    *(u16x8*)(row + base) = o;
  }
}

// ---------------- final: gather 2 expert rows x 2 K-splits, sum, LN ----------------
__global__ __launch_bounds__(256) void final_ln_kernel(
    const u16* __restrict__ Gout, const int* __restrict__ pos,
    const int* __restrict__ offsets, const float* __restrict__ g,
    const float* __restrict__ b, float* __restrict__ out) {
  const size_t SPLIT = (size_t)ROWCAP * ODIM;
  int t = blockIdx.x;
  int tid = threadIdx.x;
  int p1 = pos[t * 2 + 0];
  int p2 = pos[t * 2 + 1];
  size_t r1 = (size_t)(offsets[p1 >> 16] + (p1 & 0xFFFF)) * ODIM + tid * 4;
  size_t r2 = (size_t)(offsets[p2 >> 16] + (p2 & 0xFFFF)) * ODIM + tid * 4;
  u16x4 a0 = *(const u16x4*)(Gout + r1);
  u16x4 a1 = *(const u16x4*)(Gout + SPLIT + r1);
  u16x4 c0 = *(const u16x4*)(Gout + r2);
  u16x4 c1 = *(const u16x4*)(Gout + SPLIT + r2);
  f32x4 v;
  #pragma unroll
  for (int j = 0; j < 4; ++j)
    v[j] = bf2f(a0[j]) + bf2f(a1[j]) + bf2f(c0[j]) + bf2f(c1[j]);
  float s = v[0] + v[1] + v[2] + v[3];
  float ss = v[0] * v[0] + v[1] * v[1] + v[2] * v[2] + v[3] * v[3];
  #pragma unroll
  for (int off = 32; off; off >>= 1) { s += __shfl_xor(s, off); ss += __shfl_xor(ss, off); }
  __shared__ float rs[4], rss[4];
  int wave = tid >> 6, lane = tid & 63;
  if (lane == 0) { rs[wave] = s; rss[wave] = ss; }
  __syncthreads();
  float S = rs[0] + rs[1] + rs[2] + rs[3];
  float SS = rss[0] + rss[1] + rss[2] + rss[3];
  float mean = S * (1.f / ODIM);
  float var = SS * (1.f / ODIM) - mean * mean;
  float rstd = rsqrtf(var + 1e-5f);
  f32x4 gv = *(const f32x4*)(g + tid * 4);
  f32x4 bv = *(const f32x4*)(b + tid * 4);
  f32x4 o;
  #pragma unroll
  for (int j = 0; j < 4; ++j) o[j] = (v[j] - mean) * rstd * gv[j] + bv[j];
  *(f32x4*)(out + (size_t)t * ODIM + tid * 4) = o;
}

extern "C" void kernel_launch(void* const* d_in, const int* in_sizes, int n_in,
                              void* d_out, int out_size, void* d_ws, size_t ws_size,
                              hipStream_t stream) {
  (void)in_sizes; (void)n_in; (void)out_size; (void)ws_size;
  const float* x    = (const float*)d_in[0];
  const float* w1   = (const float*)d_in[1];
  const float* b1   = (const float*)d_in[2];
  const float* ln1g = (const float*)d_in[3];
  const float* ln1b = (const float*)d_in[4];
  const float* w2   = (const float*)d_in[5];
  const float* b2   = (const float*)d_in[6];
  const float* wg   = (const float*)d_in[7];
  const float* bg   = (const float*)d_in[8];
  const float* outg = (const float*)d_in[9];
  const float* outb = (const float*)d_in[10];
  float* out = (float*)d_out;

  char* ws = (char*)d_ws;
  size_t off = 0;
  auto alloc = [&](size_t bytes) {
    char* p = ws + off;
    off += (bytes + 255) & ~(size_t)255;
    return p;
  };
  // Region 0: xb + w1t (dead after gemm1) aliased with Gout[2] (bf16)
  size_t xb_sz  = (size_t)NTOK * IDIM * 2;                 // 16.78 MB
  size_t w1t_sz = (size_t)NEXP * HDIM * IDIM * 2;          // 67.1 MB
  size_t gout_sz = (size_t)2 * ROWCAP * ODIM * 2;          // 75.5 MB ( < xb+w1t )
  size_t reg0 = xb_sz + w1t_sz;
  if (gout_sz > reg0) reg0 = gout_sz;
  char* base0 = (char*)alloc(reg0);
  u16* xb   = (u16*)base0;
  u16* w1t  = (u16*)(base0 + xb_sz);
  u16* Gout = (u16*)base0;

  u16* w2t       = (u16*)alloc((size_t)NEXP * ODIM * HDIM * 2);
  u16* Hbuf      = (u16*)alloc((size_t)ROWCAP * HDIM * 2);
  float* combine = (float*)alloc((size_t)NTOK * NEXP * 4);
  int* tokenlist = (int*)alloc((size_t)NEXP * NTOK * 4);
  int* pos       = (int*)alloc((size_t)NTOK * 2 * 4);
  int* sel       = (int*)alloc((size_t)NTOK * 4);
  int* cnt       = (int*)alloc(64);
  int* offsets   = (int*)alloc(64);
  float* imp_partial = (float*)alloc(GATE_BLOCKS * NEXP * 4);

  transpose_convert_kernel<<<4096, 256, 0, stream>>>(w1, w2, w1t, w2t);
  gating_kernel<<<GATE_BLOCKS, 256, 0, stream>>>(x, wg, bg, combine, imp_partial, sel, xb);
  compact_kernel<<<NEXP, 256, 0, stream>>>(sel, tokenlist, cnt, pos);
  offsets_aux_kernel<<<1, 64, 0, stream>>>(cnt, imp_partial, offsets, out + (size_t)NTOK * ODIM);
  gemm1_kernel<<<dim3(HDIM / 256, MBLK), 512, 0, stream>>>(xb, w1t, b1, tokenlist, cnt, offsets, Hbuf);
  ln_gelu_kernel<<<ROWCAP, 256, 0, stream>>>(Hbuf, ln1g, ln1b, offsets);
  gemm2_kernel<<<dim3(ODIM / 256, MBLK, 2), 256, 0, stream>>>(Hbuf, w2t, b2, tokenlist, cnt, offsets, combine, Gout);
  final_ln_kernel<<<NTOK, 256, 0, stream>>>(Gout, pos, offsets, outg, outb, out);
}

// Round 13
// 518.270 us; speedup vs baseline: 1.0941x; 1.0941x over previous
//
#include <hip/hip_runtime.h>

#define NTOK 8192
#define IDIM 1024
#define HDIM 4096
#define ODIM 1024
#define NEXP 8
#define ROWCAP 18432          // NTOK*2 + NEXP*256
#define MBLK 72               // ROWCAP / 256
#define GATE_BLOCKS 512

typedef unsigned short u16;
typedef __attribute__((ext_vector_type(8))) __bf16 bf16x8;
typedef __attribute__((ext_vector_type(8))) short short8;
typedef __attribute__((ext_vector_type(4))) float f32x4;
typedef __attribute__((ext_vector_type(4))) unsigned short u16x4;
typedef __attribute__((ext_vector_type(8))) unsigned short u16x8;

__device__ __forceinline__ u16 f2bf(float f) {
  union { float f; unsigned u; } c; c.f = f;
  unsigned u = c.u;
  return (u16)((u + 0x7fffu + ((u >> 16) & 1u)) >> 16);
}
__device__ __forceinline__ float bf2f(u16 h) {
  union { unsigned u; float f; } c; c.u = ((unsigned)h) << 16;
  return c.f;
}
__device__ __forceinline__ void gload16(const void* g, void* l) {
  __builtin_amdgcn_global_load_lds((const __attribute__((address_space(1))) unsigned*)g,
                                   (__attribute__((address_space(3))) unsigned*)l, 16, 0, 0);
}

#define BARR __builtin_amdgcn_s_barrier()
#define LGKM0 asm volatile("s_waitcnt lgkmcnt(0)" ::: "memory")
#define VMW4 asm volatile("s_waitcnt vmcnt(4)" ::: "memory")
#define VMW0 asm volatile("s_waitcnt vmcnt(0)" ::: "memory")
#define CFENCE asm volatile("" ::: "memory")

#define QUAD(AF, BF, MB, NBQ)                                                   \
  _Pragma("unroll") for (int kk = 0; kk < 2; ++kk)                              \
  _Pragma("unroll") for (int f = 0; f < 4; ++f)                                 \
  _Pragma("unroll") for (int n = 0; n < 2; ++n)                                 \
    acc[(MB) + f][(NBQ) + n] = __builtin_amdgcn_mfma_f32_16x16x32_bf16(         \
        AF[f][kk], BF[n][kk], acc[(MB) + f][(NBQ) + n], 0, 0, 0);

// ============ prep: gating (blocks 0..511, atomic-free) + transpose (512..4607) ============
// Both roles <= 32.3 KB LDS. Gating is latency-bound and hides under transpose's HBM stream.
__global__ __launch_bounds__(256) void prep_kernel(
    const float* __restrict__ x, const float* __restrict__ wg, const float* __restrict__ bg,
    const float* __restrict__ w1, const float* __restrict__ w2,
    float* __restrict__ combine, float* __restrict__ imp_partial,
    int* __restrict__ sel, u16* __restrict__ xb,
    u16* __restrict__ w1t, u16* __restrict__ w2t) {
  __shared__ __align__(16) unsigned char shm[33024];
  int tid = threadIdx.x;
  if (blockIdx.x >= GATE_BLOCKS) {
    // ---- transpose role: 128x128 tiles, XOR-swizzled LDS (R8-verified) ----
    unsigned char* ldsb = shm;
    int bid = blockIdx.x - GATE_BLOCKS;
    const float* in; u16* outp; int R, C, r0, c0;
    if (bid < 2048) {
      int e = bid >> 8, t = bid & 255;
      in = w1 + (size_t)e * IDIM * HDIM; outp = w1t + (size_t)e * IDIM * HDIM;
      R = IDIM; C = HDIM;
      r0 = (t >> 5) * 128; c0 = (t & 31) * 128;
    } else {
      int b2 = bid - 2048;
      int e = b2 >> 8, t = b2 & 255;
      in = w2 + (size_t)e * HDIM * ODIM; outp = w2t + (size_t)e * HDIM * ODIM;
      R = HDIM; C = ODIM;
      r0 = (t >> 3) * 128; c0 = (t & 7) * 128;
    }
    int rr = tid >> 5, cc = (tid & 31) * 4;
    #pragma unroll
    for (int it = 0; it < 16; ++it) {
      int r = it * 8 + rr;
      f32x4 v = *(const f32x4*)(in + (size_t)(r0 + r) * C + c0 + cc);
      u16x4 o;
      #pragma unroll
      for (int j = 0; j < 4; ++j) o[j] = f2bf(v[j]);
      unsigned a = ((unsigned)(r * 256 + cc * 2)) ^ ((((unsigned)r >> 3) & 7u) << 4);
      *(u16x4*)(ldsb + a) = o;
    }
    __syncthreads();
    int rc = tid & 15, cg = tid >> 4;
    #pragma unroll
    for (int i = 0; i < 8; ++i) {
      int c = cg + i * 16;
      u16x8 o;
      #pragma unroll
      for (int k = 0; k < 8; ++k) {
        int r = rc * 8 + k;
        unsigned a = ((unsigned)(r * 256 + c * 2)) ^ ((((unsigned)r >> 3) & 7u) << 4);
        o[k] = *(const u16*)(ldsb + a);
      }
      *(u16x8*)(outp + (size_t)(c0 + c) * R + r0 + rc * 8) = o;
    }
    return;
  }
  // ---- gating role: vectorized LDS dot (wgs3[e][i4][j]), atomic-free ----
  float* wgs3 = (float*)shm;                       // 32768 B
  float (*impw)[NEXP] = (float(*)[NEXP])(shm + 32768);  // 128 B
  for (int d = tid; d < IDIM * NEXP; d += 256)
    wgs3[d] = wg[(d & 1023) * 8 + (d >> 10)];
  __syncthreads();
  int wave = tid >> 6, lane = tid & 63;
  float impacc[NEXP];
  #pragma unroll
  for (int e = 0; e < NEXP; ++e) impacc[e] = 0.f;

  #pragma unroll
  for (int it = 0; it < 4; ++it) {
    int t = blockIdx.x * 16 + wave * 4 + it;
    const float* xr = x + (size_t)t * IDIM;
    u16* xbw = xb + (size_t)t * IDIM;
    float s[NEXP];
    #pragma unroll
    for (int e = 0; e < NEXP; ++e) s[e] = 0.f;
    #pragma unroll
    for (int ii = 0; ii < 4; ++ii) {
      int base = ii * 256 + lane * 4;
      f32x4 xv = *(const f32x4*)(xr + base);
      u16x4 o;
      #pragma unroll
      for (int j = 0; j < 4; ++j) o[j] = f2bf(xv[j]);
      *(u16x4*)(xbw + base) = o;
      const float* wp = wgs3 + (size_t)(ii * 64 + lane) * 4;
      #pragma unroll
      for (int e = 0; e < NEXP; ++e) {
        f32x4 wv = *(const f32x4*)(wp + e * 1024);
        s[e] = fmaf(xv[0], wv[0], s[e]);
        s[e] = fmaf(xv[1], wv[1], s[e]);
        s[e] = fmaf(xv[2], wv[2], s[e]);
        s[e] = fmaf(xv[3], wv[3], s[e]);
      }
    }
    #pragma unroll
    for (int e = 0; e < NEXP; ++e) {
      #pragma unroll
      for (int off = 32; off; off >>= 1) s[e] += __shfl_xor(s[e], off);
    }
    if (lane == 0) {
      #pragma unroll
      for (int e = 0; e < NEXP; ++e) s[e] += bg[e];
      int i1 = 0; float v1 = s[0];
      #pragma unroll
      for (int e = 1; e < NEXP; ++e) if (s[e] > v1) { v1 = s[e]; i1 = e; }
      int i2 = -1; float v2 = -1e30f;
      #pragma unroll
      for (int e = 0; e < NEXP; ++e) if (e != i1 && s[e] > v2) { v2 = s[e]; i2 = e; }
      float p[NEXP], sum = 0.f;
      #pragma unroll
      for (int e = 0; e < NEXP; ++e) { p[e] = expf(s[e] - v1); sum += p[e]; }
      float inv = 1.f / sum;
      #pragma unroll
      for (int e = 0; e < NEXP; ++e) { p[e] *= inv; impacc[e] += p[e]; }
      float c1 = 1.f / (1.f + expf(v2 - v1));
      float c2 = 1.f - c1;
      #pragma unroll
      for (int e = 0; e < NEXP; ++e) combine[(size_t)t * NEXP + e] = 0.f;
      combine[(size_t)t * NEXP + i1] = c1;
      combine[(size_t)t * NEXP + i2] = c2;
      sel[t] = i1 | (i2 << 4);
    }
  }
  if (lane == 0) {
    #pragma unroll
    for (int e = 0; e < NEXP; ++e) impw[wave][e] = impacc[e];
  }
  __syncthreads();
  if (tid == 0) {
    #pragma unroll
    for (int e = 0; e < NEXP; ++e)
      imp_partial[blockIdx.x * NEXP + e] = impw[0][e] + impw[1][e] + impw[2][e] + impw[3][e];
  }
}

// ---------------- compact: 8 blocks (one per expert); token-ordered, deterministic ----------------
__global__ __launch_bounds__(256) void compact_kernel(
    const int* __restrict__ sel, int* __restrict__ tokenlist,
    int* __restrict__ cnt, int* __restrict__ pos) {
  __shared__ int warpsum[4];
  int e = blockIdx.x;
  int tid = threadIdx.x, lane = tid & 63, wave = tid >> 6;
  int base = 0;
  for (int chunk = 0; chunk < NTOK; chunk += 256) {
    int t = chunk + tid;
    int s = sel[t];
    int i1 = s & 15, i2 = s >> 4;
    bool m2 = (i2 == e);
    bool m = (i1 == e) || m2;
    unsigned long long bal = __ballot(m);
    int rank = __popcll(bal & ((1ull << lane) - 1ull));
    if (lane == 0) warpsum[wave] = __popcll(bal);
    __syncthreads();
    int woff = 0;
    #pragma unroll
    for (int w = 0; w < 4; ++w) if (w < wave) woff += warpsum[w];
    int total = warpsum[0] + warpsum[1] + warpsum[2] + warpsum[3];
    if (m) {
      int slot = base + woff + rank;
      tokenlist[e * NTOK + slot] = t;
      pos[t * 2 + (m2 ? 1 : 0)] = (e << 16) | slot;
    }
    base += total;
    __syncthreads();
  }
  if (tid == 0) cnt[e] = base;
}

// ---------------- offsets (pad to 256) + aux loss ----------------
__global__ __launch_bounds__(64) void offsets_aux_kernel(
    const int* __restrict__ cnt, const float* __restrict__ imp_partial,
    int* __restrict__ offsets, float* __restrict__ aux_out) {
  __shared__ float imp[NEXP];
  int tid = threadIdx.x;
  if (tid < NEXP) {
    float v = 0.f;
    for (int b = 0; b < GATE_BLOCKS; ++b) v += imp_partial[b * NEXP + tid];
    imp[tid] = v;
  }
  __syncthreads();
  if (tid == 0) {
    int off = 0;
    for (int e = 0; e < NEXP; ++e) { offsets[e] = off; off += (cnt[e] + 255) & ~255; }
    offsets[NEXP] = off;
    double im = 0.0;
    for (int e = 0; e < NEXP; ++e) im += imp[e];
    im /= NEXP;
    double iv = 0.0;
    for (int e = 0; e < NEXP; ++e) { double d = (double)imp[e] - im; iv += d * d; }
    iv /= (NEXP - 1);
    double il = sqrt(iv) / (im + 1e-6); il = il * il;
    double lm = 0.0;
    for (int e = 0; e < NEXP; ++e) lm += cnt[e];
    lm /= (double)NEXP * NTOK;
    double lv = 0.0;
    for (int e = 0; e < NEXP; ++e) { double d = (double)cnt[e] / NTOK - lm; lv += d * d; }
    lv /= (NEXP - 1);
    double ll = sqrt(lv) / (lm + 1e-6); ll = ll * ll;
    aux_out[0] = (float)(il + ll);
  }
}

// ============ GEMM1: 8-wave, 1-barrier/phase schedule (R8-verified) ============
__global__ __launch_bounds__(512, 2) void gemm1_kernel(
    const u16* __restrict__ xb, const u16* __restrict__ w1t, const float* __restrict__ b1,
    const int* __restrict__ tokenlist, const int* __restrict__ cnt,
    const int* __restrict__ offsets, u16* __restrict__ Hbuf) {
  __shared__ __align__(64) unsigned char sm[139264];
  const int NB = HDIM / 256;       // 16
  const int TT = IDIM / 64;        // 16
  int nwg = NB * MBLK;
  int flat = blockIdx.y * NB + blockIdx.x;
  int q = nwg >> 3;
  int swzb = (flat & 7) * q + (flat >> 3);
  int mb = swzb / NB, cb = swzb % NB;
  int grb = mb * 256;
  if (grb >= offsets[NEXP]) return;
  int e = 0;
  #pragma unroll
  for (int k = 0; k < NEXP - 1; ++k) if (grb >= offsets[k + 1]) e = k + 1;
  int lr0 = grb - offsets[e];
  int cnt_e = cnt[e];
  int tid = threadIdx.x, lane = tid & 63, wave = tid >> 6;
  int wr = wave >> 2, wc = wave & 3;

  const int* tl = tokenlist + e * NTOK;
  int colel = (((tid & 7) ^ ((tid >> 3) & 7)) << 3);
  const u16* pA[4]; const u16* pB[4];
  #pragma unroll
  for (int h = 0; h < 2; ++h)
    #pragma unroll
    for (int j = 0; j < 2; ++j) {
      int rowT = h * 128 + j * 64 + (tid >> 3);
      int tok = tl[min(lr0 + rowT, cnt_e - 1)];
      pA[h * 2 + j] = xb + (size_t)tok * IDIM + colel;
      pB[h * 2 + j] = w1t + ((size_t)e * HDIM + cb * 256 + rowT) * IDIM + colel;
    }
  unsigned ldsw = wave * 1024;

  #define STAGE_A(T, H) { unsigned d = (((T) & 1) << 16) + (H) * 16384 + ldsw; \
      gload16(pA[(H)*2+0] + (T)*64, sm + d); gload16(pA[(H)*2+1] + (T)*64, sm + d + 8192); }
  #define STAGE_B(T, H) { unsigned d = (((T) & 1) << 16) + 32768 + (H) * 16384 + ldsw; \
      gload16(pB[(H)*2+0] + (T)*64, sm + d); gload16(pB[(H)*2+1] + (T)*64, sm + d + 8192); }

  int rA = lane & 15;
  int swz = (((lane >> 4) ^ (lane & 7)) << 4);
  int aOff = wr * 16384 + rA * 128 + swz;
  int bOff = 32768 + wc * 8192 + rA * 128 + swz;

  f32x4 acc[8][4];
  #pragma unroll
  for (int m = 0; m < 8; ++m)
    #pragma unroll
    for (int n = 0; n < 4; ++n) acc[m][n] = (f32x4){0.f, 0.f, 0.f, 0.f};
  bf16x8 af[4][2], bf0[2][2], bf1[2][2];

  STAGE_A(0, 0); STAGE_A(0, 1); STAGE_B(0, 0); STAGE_B(0, 1);
  CFENCE;
  STAGE_B(1, 0); STAGE_B(1, 1);
  VMW4; BARR;

  for (int t = 0; t < TT; ++t) {
    int bufb = (t & 1) << 16;
    #pragma unroll
    for (int f = 0; f < 4; ++f) {
      int o = bufb + aOff + f * 2048;
      af[f][0] = *(const bf16x8*)(sm + o);
      af[f][1] = *(const bf16x8*)(sm + (o ^ 64));
    }
    #pragma unroll
    for (int n = 0; n < 2; ++n) {
      int o = bufb + bOff + n * 2048;
      bf0[n][0] = *(const bf16x8*)(sm + o);
      bf0[n][1] = *(const bf16x8*)(sm + (o ^ 64));
    }
    if (t + 1 < TT) STAGE_A(t + 1, 0);
    BARR; LGKM0;
    __builtin_amdgcn_s_setprio(1);
    QUAD(af, bf0, 0, 0);
    __builtin_amdgcn_s_setprio(0);
    #pragma unroll
    for (int n = 0; n < 2; ++n) {
      int o = bufb + bOff + 4096 + n * 2048;
      bf1[n][0] = *(const bf16x8*)(sm + o);
      bf1[n][1] = *(const bf16x8*)(sm + (o ^ 64));
    }
    if (t + 1 < TT) STAGE_A(t + 1, 1);
    BARR; LGKM0;
    __builtin_amdgcn_s_setprio(1);
    QUAD(af, bf1, 0, 2);
    __builtin_amdgcn_s_setprio(0);
    #pragma unroll
    for (int f = 0; f < 4; ++f) {
      int o = bufb + aOff + 8192 + f * 2048;
      af[f][0] = *(const bf16x8*)(sm + o);
      af[f][1] = *(const bf16x8*)(sm + (o ^ 64));
    }
    BARR; LGKM0;
    __builtin_amdgcn_s_setprio(1);
    QUAD(af, bf1, 4, 2);
    __builtin_amdgcn_s_setprio(0);
    if (t + 2 < TT) { STAGE_B(t + 2, 0); STAGE_B(t + 2, 1); }
    __builtin_amdgcn_s_setprio(1);
    QUAD(af, bf0, 4, 0);
    __builtin_amdgcn_s_setprio(0);
    if (t + 2 < TT) { VMW4; } else { VMW0; }
    BARR;
  }

  #pragma unroll
  for (int n = 0; n < 4; ++n) {
    int colb = (wc * 64 + n * 16 + (lane & 15)) * 2;
    float bias = b1[e * HDIM + cb * 256 + wc * 64 + n * 16 + (lane & 15)];
    #pragma unroll
    for (int m = 0; m < 8; ++m) {
      int row = wr * 128 + m * 16 + (lane >> 4) * 4;
      #pragma unroll
      for (int j = 0; j < 4; ++j)
        *(u16*)(sm + (row + j) * 544 + colb) = f2bf(acc[m][n][j] + bias);
    }
  }
  BARR;
  #pragma unroll
  for (int p = 0; p < 16; ++p) {
    int cidx = p * 512 + tid;
    int row = cidx >> 5, cch = cidx & 31;
    u16x8 v = *(const u16x8*)(sm + row * 544 + cch * 16);
    *(u16x8*)(Hbuf + (size_t)(grb + row) * HDIM + cb * 256 + cch * 8) = v;
  }
  #undef STAGE_A
  #undef STAGE_B
}

// ============ GEMM2: 8-wave, 1-barrier/phase, split-K=2, dense bf16 out (R10-verified) ============
__global__ __launch_bounds__(512, 2) void gemm2_kernel(
    const u16* __restrict__ Hbuf, const u16* __restrict__ w2t, const float* __restrict__ b2,
    const int* __restrict__ tokenlist, const int* __restrict__ cnt,
    const int* __restrict__ offsets, const float* __restrict__ combine,
    u16* __restrict__ Gout) {
  __shared__ __align__(64) unsigned char sm[139264];
  const int NB = ODIM / 256;       // 4
  const int TT = (HDIM / 2) / 64;  // 32 per split
  int nwg = NB * MBLK;
  int flat = blockIdx.y * NB + blockIdx.x;
  int q = nwg >> 3;
  int swzb = (flat & 7) * q + (flat >> 3);
  int mb = swzb / NB, cb = swzb % NB;
  int ks = blockIdx.z;
  int grb = mb * 256;
  if (grb >= offsets[NEXP]) return;
  int e = 0;
  #pragma unroll
  for (int k = 0; k < NEXP - 1; ++k) if (grb >= offsets[k + 1]) e = k + 1;
  int lr0 = grb - offsets[e];
  int cnt_e = cnt[e];
  int tid = threadIdx.x, lane = tid & 63, wave = tid >> 6;
  int wr = wave >> 2, wc = wave & 3;
  size_t ksOff = (size_t)ks * (HDIM / 2);
  u16* Gk = Gout + (size_t)ks * ROWCAP * ODIM;

  int colel = (((tid & 7) ^ ((tid >> 3) & 7)) << 3);
  const u16* pA[4]; const u16* pB[4];
  #pragma unroll
  for (int h = 0; h < 2; ++h)
    #pragma unroll
    for (int j = 0; j < 2; ++j) {
      int rowT = h * 128 + j * 64 + (tid >> 3);
      pA[h * 2 + j] = Hbuf + (size_t)(grb + rowT) * HDIM + ksOff + colel;
      pB[h * 2 + j] = w2t + ((size_t)e * ODIM + cb * 256 + rowT) * HDIM + ksOff + colel;
    }
  unsigned ldsw = wave * 1024;

  #define STAGE_A(T, H) { unsigned d = (((T) & 1) << 16) + (H) * 16384 + ldsw; \
      gload16(pA[(H)*2+0] + (T)*64, sm + d); gload16(pA[(H)*2+1] + (T)*64, sm + d + 8192); }
  #define STAGE_B(T, H) { unsigned d = (((T) & 1) << 16) + 32768 + (H) * 16384 + ldsw; \
      gload16(pB[(H)*2+0] + (T)*64, sm + d); gload16(pB[(H)*2+1] + (T)*64, sm + d + 8192); }

  int rA = lane & 15;
  int swz = (((lane >> 4) ^ (lane & 7)) << 4);
  int aOff = wr * 16384 + rA * 128 + swz;
  int bOff = 32768 + wc * 8192 + rA * 128 + swz;

  f32x4 acc[8][4];
  #pragma unroll
  for (int m = 0; m < 8; ++m)
    #pragma unroll
    for (int n = 0; n < 4; ++n) acc[m][n] = (f32x4){0.f, 0.f, 0.f, 0.f};
  bf16x8 af[4][2], bf0[2][2], bf1[2][2];

  STAGE_A(0, 0); STAGE_A(0, 1); STAGE_B(0, 0); STAGE_B(0, 1);
  CFENCE;
  STAGE_B(1, 0); STAGE_B(1, 1);
  VMW4; BARR;

  for (int t = 0; t < TT; ++t) {
    int bufb = (t & 1) << 16;
    #pragma unroll
    for (int f = 0; f < 4; ++f) {
      int o = bufb + aOff + f * 2048;
      af[f][0] = *(const bf16x8*)(sm + o);
      af[f][1] = *(const bf16x8*)(sm + (o ^ 64));
    }
    #pragma unroll
    for (int n = 0; n < 2; ++n) {
      int o = bufb + bOff + n * 2048;
      bf0[n][0] = *(const bf16x8*)(sm + o);
      bf0[n][1] = *(const bf16x8*)(sm + (o ^ 64));
    }
    if (t + 1 < TT) STAGE_A(t + 1, 0);
    BARR; LGKM0;
    __builtin_amdgcn_s_setprio(1);
    QUAD(af, bf0, 0, 0);
    __builtin_amdgcn_s_setprio(0);
    #pragma unroll
    for (int n = 0; n < 2; ++n) {
      int o = bufb + bOff + 4096 + n * 2048;
      bf1[n][0] = *(const bf16x8*)(sm + o);
      bf1[n][1] = *(const bf16x8*)(sm + (o ^ 64));
    }
    if (t + 1 < TT) STAGE_A(t + 1, 1);
    BARR; LGKM0;
    __builtin_amdgcn_s_setprio(1);
    QUAD(af, bf1, 0, 2);
    __builtin_amdgcn_s_setprio(0);
    #pragma unroll
    for (int f = 0; f < 4; ++f) {
      int o = bufb + aOff + 8192 + f * 2048;
      af[f][0] = *(const bf16x8*)(sm + o);
      af[f][1] = *(const bf16x8*)(sm + (o ^ 64));
    }
    BARR; LGKM0;
    __builtin_amdgcn_s_setprio(1);
    QUAD(af, bf1, 4, 2);
    __builtin_amdgcn_s_setprio(0);
    if (t + 2 < TT) { STAGE_B(t + 2, 0); STAGE_B(t + 2, 1); }
    __builtin_amdgcn_s_setprio(1);
    QUAD(af, bf0, 4, 0);
    __builtin_amdgcn_s_setprio(0);
    if (t + 2 < TT) { VMW4; } else { VMW0; }
    BARR;
  }

  const int* tl = tokenlist + e * NTOK;
  float bias_n[4];
  #pragma unroll
  for (int n = 0; n < 4; ++n)
    bias_n[n] = (ks == 0) ? b2[e * ODIM + cb * 256 + wc * 64 + n * 16 + (lane & 15)] : 0.f;
  #pragma unroll
  for (int m = 0; m < 8; ++m) {
    #pragma unroll
    for (int j = 0; j < 4; ++j) {
      int rr = wr * 128 + m * 16 + (lane >> 4) * 4 + j;
      int tok = tl[min(lr0 + rr, cnt_e - 1)];
      float c = combine[(size_t)tok * NEXP + e];
      #pragma unroll
      for (int n = 0; n < 4; ++n)
        *(u16*)(sm + rr * 544 + (wc * 64 + n * 16 + (lane & 15)) * 2) =
            f2bf(c * (acc[m][n][j] + bias_n[n]));
    }
  }
  BARR;
  #pragma unroll
  for (int p = 0; p < 16; ++p) {
    int cidx = p * 512 + tid;
    int row = cidx >> 5, cch = cidx & 31;
    u16x8 v = *(const u16x8*)(sm + row * 544 + cch * 16);
    *(u16x8*)(Gk + (size_t)(grb + row) * ODIM + cb * 256 + cch * 8) = v;
  }
  #undef STAGE_A
  #undef STAGE_B
}

// ---------------- LN + exact GELU in place ----------------
__global__ __launch_bounds__(256) void ln_gelu_kernel(
    u16* __restrict__ Hbuf, const float* __restrict__ g, const float* __restrict__ b,
    const int* __restrict__ offsets) {
  int r = blockIdx.x;
  if (r >= offsets[NEXP]) return;
  int e = 0;
  #pragma unroll
  for (int k = 0; k < NEXP - 1; ++k) if (r >= offsets[k + 1]) e = k + 1;
  u16* row = Hbuf + (size_t)r * HDIM;
  const float* ge = g + e * HDIM;
  const float* be = b + e * HDIM;
  int tid = threadIdx.x;
  float s = 0.f, ss = 0.f;
  short8 v[2];
  #pragma unroll
  for (int it = 0; it < 2; ++it) {
    v[it] = *(const short8*)(row + (tid + it * 256) * 8);
    #pragma unroll
    for (int j = 0; j < 8; ++j) { float f = bf2f((u16)v[it][j]); s += f; ss += f * f; }
  }
  #pragma unroll
  for (int off = 32; off; off >>= 1) { s += __shfl_xor(s, off); ss += __shfl_xor(ss, off); }
  __shared__ float rs[4], rss[4];
  int wave = tid >> 6, lane = tid & 63;
  if (lane == 0) { rs[wave] = s; rss[wave] = ss; }
  __syncthreads();
  float S = rs[0] + rs[1] + rs[2] + rs[3];
  float SS = rss[0] + rss[1] + rss[2] + rss[3];
  float mean = S * (1.f / HDIM);
  float var = SS * (1.f / HDIM) - mean * mean;
  float rstd = rsqrtf(var + 1e-5f);
  #pragma unroll
  for (int it = 0; it < 2; ++it) {
    int base = (tid + it * 256) * 8;
    f32x4 g0 = *(const f32x4*)(ge + base);
    f32x4 g1 = *(const f32x4*)(ge + base + 4);
    f32x4 b0 = *(const f32x4*)(be + base);
    f32x4 b1v = *(const f32x4*)(be + base + 4);
    u16x8 o;
    #pragma unroll
    for (int j = 0; j < 8; ++j) {
      float f = bf2f((u16)v[it][j]);
      float gg = j < 4 ? g0[j & 3] : g1[j & 3];
      float bb = j < 4 ? b0[j & 3] : b1v[j & 3];
      float y = (f - mean) * rstd * gg + bb;
      float gel = 0.5f * y * (1.f + erff(y * 0.70710678118654752f));
      o[j] = f2bf(gel);
    }
    *(u16x8*)(row + base) = o;
  }
}

// ---------------- final: gather 2 expert rows x 2 K-splits, sum, LN ----------------
__global__ __launch_bounds__(256) void final_ln_kernel(
    const u16* __restrict__ Gout, const int* __restrict__ pos,
    const int* __restrict__ offsets, const float* __restrict__ g,
    const float* __restrict__ b, float* __restrict__ out) {
  const size_t SPLIT = (size_t)ROWCAP * ODIM;
  int t = blockIdx.x;
  int tid = threadIdx.x;
  int p1 = pos[t * 2 + 0];
  int p2 = pos[t * 2 + 1];
  size_t r1 = (size_t)(offsets[p1 >> 16] + (p1 & 0xFFFF)) * ODIM + tid * 4;
  size_t r2 = (size_t)(offsets[p2 >> 16] + (p2 & 0xFFFF)) * ODIM + tid * 4;
  u16x4 a0 = *(const u16x4*)(Gout + r1);
  u16x4 a1 = *(const u16x4*)(Gout + SPLIT + r1);
  u16x4 c0 = *(const u16x4*)(Gout + r2);
  u16x4 c1 = *(const u16x4*)(Gout + SPLIT + r2);
  f32x4 v;
  #pragma unroll
  for (int j = 0; j < 4; ++j)
    v[j] = bf2f(a0[j]) + bf2f(a1[j]) + bf2f(c0[j]) + bf2f(c1[j]);
  float s = v[0] + v[1] + v[2] + v[3];
  float ss = v[0] * v[0] + v[1] * v[1] + v[2] * v[2] + v[3] * v[3];
  #pragma unroll
  for (int off = 32; off; off >>= 1) { s += __shfl_xor(s, off); ss += __shfl_xor(ss, off); }
  __shared__ float rs[4], rss[4];
  int wave = tid >> 6, lane = tid & 63;
  if (lane == 0) { rs[wave] = s; rss[wave] = ss; }
  __syncthreads();
  float S = rs[0] + rs[1] + rs[2] + rs[3];
  float SS = rss[0] + rss[1] + rss[2] + rss[3];
  float mean = S * (1.f / ODIM);
  float var = SS * (1.f / ODIM) - mean * mean;
  float rstd = rsqrtf(var + 1e-5f);
  f32x4 gv = *(const f32x4*)(g + tid * 4);
  f32x4 bv = *(const f32x4*)(b + tid * 4);
  f32x4 o;
  #pragma unroll
  for (int j = 0; j < 4; ++j) o[j] = (v[j] - mean) * rstd * gv[j] + bv[j];
  *(f32x4*)(out + (size_t)t * ODIM + tid * 4) = o;
}

extern "C" void kernel_launch(void* const* d_in, const int* in_sizes, int n_in,
                              void* d_out, int out_size, void* d_ws, size_t ws_size,
                              hipStream_t stream) {
  (void)in_sizes; (void)n_in; (void)out_size; (void)ws_size;
  const float* x    = (const float*)d_in[0];
  const float* w1   = (const float*)d_in[1];
  const float* b1   = (const float*)d_in[2];
  const float* ln1g = (const float*)d_in[3];
  const float* ln1b = (const float*)d_in[4];
  const float* w2   = (const float*)d_in[5];
  const float* b2   = (const float*)d_in[6];
  const float* wg   = (const float*)d_in[7];
  const float* bg   = (const float*)d_in[8];
  const float* outg = (const float*)d_in[9];
  const float* outb = (const float*)d_in[10];
  float* out = (float*)d_out;

  char* ws = (char*)d_ws;
  size_t off = 0;
  auto alloc = [&](size_t bytes) {
    char* p = ws + off;
    off += (bytes + 255) & ~(size_t)255;
    return p;
  };
  // Region 0: xb + w1t (dead after gemm1) aliased with Gout[2] (bf16)
  size_t xb_sz  = (size_t)NTOK * IDIM * 2;                 // 16.78 MB
  size_t w1t_sz = (size_t)NEXP * HDIM * IDIM * 2;          // 67.1 MB
  size_t gout_sz = (size_t)2 * ROWCAP * ODIM * 2;          // 75.5 MB ( < xb+w1t )
  size_t reg0 = xb_sz + w1t_sz;
  if (gout_sz > reg0) reg0 = gout_sz;
  char* base0 = (char*)alloc(reg0);
  u16* xb   = (u16*)base0;
  u16* w1t  = (u16*)(base0 + xb_sz);
  u16* Gout = (u16*)base0;

  u16* w2t       = (u16*)alloc((size_t)NEXP * ODIM * HDIM * 2);
  u16* Hbuf      = (u16*)alloc((size_t)ROWCAP * HDIM * 2);
  float* combine = (float*)alloc((size_t)NTOK * NEXP * 4);
  int* tokenlist = (int*)alloc((size_t)NEXP * NTOK * 4);
  int* pos       = (int*)alloc((size_t)NTOK * 2 * 4);
  int* sel       = (int*)alloc((size_t)NTOK * 4);
  int* cnt       = (int*)alloc(64);
  int* offsets   = (int*)alloc(64);
  float* imp_partial = (float*)alloc(GATE_BLOCKS * NEXP * 4);

  prep_kernel<<<GATE_BLOCKS + 4096, 256, 0, stream>>>(
      x, wg, bg, w1, w2, combine, imp_partial, sel, xb, w1t, w2t);
  compact_kernel<<<NEXP, 256, 0, stream>>>(sel, tokenlist, cnt, pos);
  offsets_aux_kernel<<<1, 64, 0, stream>>>(cnt, imp_partial, offsets, out + (size_t)NTOK * ODIM);
  gemm1_kernel<<<dim3(HDIM / 256, MBLK), 512, 0, stream>>>(xb, w1t, b1, tokenlist, cnt, offsets, Hbuf);
  ln_gelu_kernel<<<ROWCAP, 256, 0, stream>>>(Hbuf, ln1g, ln1b, offsets);
  gemm2_kernel<<<dim3(ODIM / 256, MBLK, 2), 512, 0, stream>>>(Hbuf, w2t, b2, tokenlist, cnt, offsets, combine, Gout);
  final_ln_kernel<<<NTOK, 256, 0, stream>>>(Gout, pos, offsets, outg, outb, out);
}

// Round 14
// 512.322 us; speedup vs baseline: 1.1068x; 1.0116x over previous
//
#include <hip/hip_runtime.h>

#define NTOK 8192
#define IDIM 1024
#define HDIM 4096
#define ODIM 1024
#define NEXP 8
#define ROWCAP 18432          // NTOK*2 + NEXP*256
#define MBLK 72               // ROWCAP / 256
#define GATE_BLOCKS 512

typedef unsigned short u16;
typedef __attribute__((ext_vector_type(8))) __bf16 bf16x8;
typedef __attribute__((ext_vector_type(8))) short short8;
typedef __attribute__((ext_vector_type(4))) float f32x4;
typedef __attribute__((ext_vector_type(4))) unsigned short u16x4;
typedef __attribute__((ext_vector_type(8))) unsigned short u16x8;

__device__ __forceinline__ u16 f2bf(float f) {
  union { float f; unsigned u; } c; c.f = f;
  unsigned u = c.u;
  return (u16)((u + 0x7fffu + ((u >> 16) & 1u)) >> 16);
}
__device__ __forceinline__ float bf2f(u16 h) {
  union { unsigned u; float f; } c; c.u = ((unsigned)h) << 16;
  return c.f;
}
__device__ __forceinline__ void gload16(const void* g, void* l) {
  __builtin_amdgcn_global_load_lds((const __attribute__((address_space(1))) unsigned*)g,
                                   (__attribute__((address_space(3))) unsigned*)l, 16, 0, 0);
}

#define BARR __builtin_amdgcn_s_barrier()
#define LGKM0 asm volatile("s_waitcnt lgkmcnt(0)" ::: "memory")
#define SCHEDB __builtin_amdgcn_sched_barrier(0)
#define VMW4 asm volatile("s_waitcnt vmcnt(4)" ::: "memory")
#define VMW0 asm volatile("s_waitcnt vmcnt(0)" ::: "memory")
#define CFENCE asm volatile("" ::: "memory")

#define QUAD(AF, BF, MB, NBQ)                                                   \
  _Pragma("unroll") for (int kk = 0; kk < 2; ++kk)                              \
  _Pragma("unroll") for (int f = 0; f < 4; ++f)                                 \
  _Pragma("unroll") for (int n = 0; n < 2; ++n)                                 \
    acc[(MB) + f][(NBQ) + n] = __builtin_amdgcn_mfma_f32_16x16x32_bf16(         \
        AF[f][kk], BF[n][kk], acc[(MB) + f][(NBQ) + n], 0, 0, 0);

// ============ prep: gating (blocks 0..511, atomic-free) + transpose (512..4607) ============
__global__ __launch_bounds__(256) void prep_kernel(
    const float* __restrict__ x, const float* __restrict__ wg, const float* __restrict__ bg,
    const float* __restrict__ w1, const float* __restrict__ w2,
    float* __restrict__ combine, float* __restrict__ imp_partial,
    int* __restrict__ sel, u16* __restrict__ xb,
    u16* __restrict__ w1t, u16* __restrict__ w2t) {
  __shared__ __align__(16) unsigned char shm[33024];
  int tid = threadIdx.x;
  if (blockIdx.x >= GATE_BLOCKS) {
    unsigned char* ldsb = shm;
    int bid = blockIdx.x - GATE_BLOCKS;
    const float* in; u16* outp; int R, C, r0, c0;
    if (bid < 2048) {
      int e = bid >> 8, t = bid & 255;
      in = w1 + (size_t)e * IDIM * HDIM; outp = w1t + (size_t)e * IDIM * HDIM;
      R = IDIM; C = HDIM;
      r0 = (t >> 5) * 128; c0 = (t & 31) * 128;
    } else {
      int b2 = bid - 2048;
      int e = b2 >> 8, t = b2 & 255;
      in = w2 + (size_t)e * HDIM * ODIM; outp = w2t + (size_t)e * HDIM * ODIM;
      R = HDIM; C = ODIM;
      r0 = (t >> 3) * 128; c0 = (t & 7) * 128;
    }
    int rr = tid >> 5, cc = (tid & 31) * 4;
    #pragma unroll
    for (int it = 0; it < 16; ++it) {
      int r = it * 8 + rr;
      f32x4 v = *(const f32x4*)(in + (size_t)(r0 + r) * C + c0 + cc);
      u16x4 o;
      #pragma unroll
      for (int j = 0; j < 4; ++j) o[j] = f2bf(v[j]);
      unsigned a = ((unsigned)(r * 256 + cc * 2)) ^ ((((unsigned)r >> 3) & 7u) << 4);
      *(u16x4*)(ldsb + a) = o;
    }
    __syncthreads();
    int rc = tid & 15, cg = tid >> 4;
    #pragma unroll
    for (int i = 0; i < 8; ++i) {
      int c = cg + i * 16;
      u16x8 o;
      #pragma unroll
      for (int k = 0; k < 8; ++k) {
        int r = rc * 8 + k;
        unsigned a = ((unsigned)(r * 256 + c * 2)) ^ ((((unsigned)r >> 3) & 7u) << 4);
        o[k] = *(const u16*)(ldsb + a);
      }
      *(u16x8*)(outp + (size_t)(c0 + c) * R + r0 + rc * 8) = o;
    }
    return;
  }
  float* wgs3 = (float*)shm;
  float (*impw)[NEXP] = (float(*)[NEXP])(shm + 32768);
  for (int d = tid; d < IDIM * NEXP; d += 256)
    wgs3[d] = wg[(d & 1023) * 8 + (d >> 10)];
  __syncthreads();
  int wave = tid >> 6, lane = tid & 63;
  float impacc[NEXP];
  #pragma unroll
  for (int e = 0; e < NEXP; ++e) impacc[e] = 0.f;

  #pragma unroll
  for (int it = 0; it < 4; ++it) {
    int t = blockIdx.x * 16 + wave * 4 + it;
    const float* xr = x + (size_t)t * IDIM;
    u16* xbw = xb + (size_t)t * IDIM;
    float s[NEXP];
    #pragma unroll
    for (int e = 0; e < NEXP; ++e) s[e] = 0.f;
    #pragma unroll
    for (int ii = 0; ii < 4; ++ii) {
      int base = ii * 256 + lane * 4;
      f32x4 xv = *(const f32x4*)(xr + base);
      u16x4 o;
      #pragma unroll
      for (int j = 0; j < 4; ++j) o[j] = f2bf(xv[j]);
      *(u16x4*)(xbw + base) = o;
      const float* wp = wgs3 + (size_t)(ii * 64 + lane) * 4;
      #pragma unroll
      for (int e = 0; e < NEXP; ++e) {
        f32x4 wv = *(const f32x4*)(wp + e * 1024);
        s[e] = fmaf(xv[0], wv[0], s[e]);
        s[e] = fmaf(xv[1], wv[1], s[e]);
        s[e] = fmaf(xv[2], wv[2], s[e]);
        s[e] = fmaf(xv[3], wv[3], s[e]);
      }
    }
    #pragma unroll
    for (int e = 0; e < NEXP; ++e) {
      #pragma unroll
      for (int off = 32; off; off >>= 1) s[e] += __shfl_xor(s[e], off);
    }
    if (lane == 0) {
      #pragma unroll
      for (int e = 0; e < NEXP; ++e) s[e] += bg[e];
      int i1 = 0; float v1 = s[0];
      #pragma unroll
      for (int e = 1; e < NEXP; ++e) if (s[e] > v1) { v1 = s[e]; i1 = e; }
      int i2 = -1; float v2 = -1e30f;
      #pragma unroll
      for (int e = 0; e < NEXP; ++e) if (e != i1 && s[e] > v2) { v2 = s[e]; i2 = e; }
      float p[NEXP], sum = 0.f;
      #pragma unroll
      for (int e = 0; e < NEXP; ++e) { p[e] = expf(s[e] - v1); sum += p[e]; }
      float inv = 1.f / sum;
      #pragma unroll
      for (int e = 0; e < NEXP; ++e) { p[e] *= inv; impacc[e] += p[e]; }
      float c1 = 1.f / (1.f + expf(v2 - v1));
      float c2 = 1.f - c1;
      #pragma unroll
      for (int e = 0; e < NEXP; ++e) combine[(size_t)t * NEXP + e] = 0.f;
      combine[(size_t)t * NEXP + i1] = c1;
      combine[(size_t)t * NEXP + i2] = c2;
      sel[t] = i1 | (i2 << 4);
    }
  }
  if (lane == 0) {
    #pragma unroll
    for (int e = 0; e < NEXP; ++e) impw[wave][e] = impacc[e];
  }
  __syncthreads();
  if (tid == 0) {
    #pragma unroll
    for (int e = 0; e < NEXP; ++e)
      imp_partial[blockIdx.x * NEXP + e] = impw[0][e] + impw[1][e] + impw[2][e] + impw[3][e];
  }
}

// ---------------- compact: 8 blocks (one per expert); token-ordered, deterministic ----------------
__global__ __launch_bounds__(256) void compact_kernel(
    const int* __restrict__ sel, int* __restrict__ tokenlist,
    int* __restrict__ cnt, int* __restrict__ pos) {
  __shared__ int warpsum[4];
  int e = blockIdx.x;
  int tid = threadIdx.x, lane = tid & 63, wave = tid >> 6;
  int base = 0;
  for (int chunk = 0; chunk < NTOK; chunk += 256) {
    int t = chunk + tid;
    int s = sel[t];
    int i1 = s & 15, i2 = s >> 4;
    bool m2 = (i2 == e);
    bool m = (i1 == e) || m2;
    unsigned long long bal = __ballot(m);
    int rank = __popcll(bal & ((1ull << lane) - 1ull));
    if (lane == 0) warpsum[wave] = __popcll(bal);
    __syncthreads();
    int woff = 0;
    #pragma unroll
    for (int w = 0; w < 4; ++w) if (w < wave) woff += warpsum[w];
    int total = warpsum[0] + warpsum[1] + warpsum[2] + warpsum[3];
    if (m) {
      int slot = base + woff + rank;
      tokenlist[e * NTOK + slot] = t;
      pos[t * 2 + (m2 ? 1 : 0)] = (e << 16) | slot;
    }
    base += total;
    __syncthreads();
  }
  if (tid == 0) cnt[e] = base;
}

// ---------------- offsets (pad to 256) + aux loss ----------------
__global__ __launch_bounds__(64) void offsets_aux_kernel(
    const int* __restrict__ cnt, const float* __restrict__ imp_partial,
    int* __restrict__ offsets, float* __restrict__ aux_out) {
  __shared__ float imp[NEXP];
  int tid = threadIdx.x;
  if (tid < NEXP) {
    float v = 0.f;
    for (int b = 0; b < GATE_BLOCKS; ++b) v += imp_partial[b * NEXP + tid];
    imp[tid] = v;
  }
  __syncthreads();
  if (tid == 0) {
    int off = 0;
    for (int e = 0; e < NEXP; ++e) { offsets[e] = off; off += (cnt[e] + 255) & ~255; }
    offsets[NEXP] = off;
    double im = 0.0;
    for (int e = 0; e < NEXP; ++e) im += imp[e];
    im /= NEXP;
    double iv = 0.0;
    for (int e = 0; e < NEXP; ++e) { double d = (double)imp[e] - im; iv += d * d; }
    iv /= (NEXP - 1);
    double il = sqrt(iv) / (im + 1e-6); il = il * il;
    double lm = 0.0;
    for (int e = 0; e < NEXP; ++e) lm += cnt[e];
    lm /= (double)NEXP * NTOK;
    double lv = 0.0;
    for (int e = 0; e < NEXP; ++e) { double d = (double)cnt[e] / NTOK - lm; lv += d * d; }
    lv /= (NEXP - 1);
    double ll = sqrt(lv) / (lm + 1e-6); ll = ll * ll;
    aux_out[0] = (float)(il + ll);
  }
}

// ============ GEMM1: 1-barrier-per-K-tile (sync-minimal) ============
// Tile: reads(af-lo,bf0,bf1)+stageA(t+1) | LGKM0 | 32 MFMA | af-hi reads | LGKM0 |
//       32 MFMA | stageB(t+2) | VMW4 | BARR.
// Cross-wave safety: VMW4 precedes BARR -> all waves' stages drained at barrier.
// B(t+2) staged after 64 MFMA -> every wave's bf reads complete (structural margin).
__global__ __launch_bounds__(512, 2) void gemm1_kernel(
    const u16* __restrict__ xb, const u16* __restrict__ w1t, const float* __restrict__ b1,
    const int* __restrict__ tokenlist, const int* __restrict__ cnt,
    const int* __restrict__ offsets, u16* __restrict__ Hbuf) {
  __shared__ __align__(64) unsigned char sm[139264];
  const int NB = HDIM / 256;       // 16
  const int TT = IDIM / 64;        // 16
  int nwg = NB * MBLK;
  int flat = blockIdx.y * NB + blockIdx.x;
  int q = nwg >> 3;
  int swzb = (flat & 7) * q + (flat >> 3);
  int mb = swzb / NB, cb = swzb % NB;
  int grb = mb * 256;
  if (grb >= offsets[NEXP]) return;
  int e = 0;
  #pragma unroll
  for (int k = 0; k < NEXP - 1; ++k) if (grb >= offsets[k + 1]) e = k + 1;
  int lr0 = grb - offsets[e];
  int cnt_e = cnt[e];
  int tid = threadIdx.x, lane = tid & 63, wave = tid >> 6;
  int wr = wave >> 2, wc = wave & 3;

  const int* tl = tokenlist + e * NTOK;
  int colel = (((tid & 7) ^ ((tid >> 3) & 7)) << 3);
  const u16* pA[4]; const u16* pB[4];
  #pragma unroll
  for (int h = 0; h < 2; ++h)
    #pragma unroll
    for (int j = 0; j < 2; ++j) {
      int rowT = h * 128 + j * 64 + (tid >> 3);
      int tok = tl[min(lr0 + rowT, cnt_e - 1)];
      pA[h * 2 + j] = xb + (size_t)tok * IDIM + colel;
      pB[h * 2 + j] = w1t + ((size_t)e * HDIM + cb * 256 + rowT) * IDIM + colel;
    }
  unsigned ldsw = wave * 1024;

  #define STAGE_A(T, H) { unsigned d = (((T) & 1) << 16) + (H) * 16384 + ldsw; \
      gload16(pA[(H)*2+0] + (T)*64, sm + d); gload16(pA[(H)*2+1] + (T)*64, sm + d + 8192); }
  #define STAGE_B(T, H) { unsigned d = (((T) & 1) << 16) + 32768 + (H) * 16384 + ldsw; \
      gload16(pB[(H)*2+0] + (T)*64, sm + d); gload16(pB[(H)*2+1] + (T)*64, sm + d + 8192); }

  int rA = lane & 15;
  int swz = (((lane >> 4) ^ (lane & 7)) << 4);
  int aOff = wr * 16384 + rA * 128 + swz;
  int bOff = 32768 + wc * 8192 + rA * 128 + swz;

  f32x4 acc[8][4];
  #pragma unroll
  for (int m = 0; m < 8; ++m)
    #pragma unroll
    for (int n = 0; n < 4; ++n) acc[m][n] = (f32x4){0.f, 0.f, 0.f, 0.f};
  bf16x8 af[4][2], bf0[2][2], bf1[2][2];

  STAGE_A(0, 0); STAGE_A(0, 1); STAGE_B(0, 0); STAGE_B(0, 1);
  CFENCE;
  STAGE_B(1, 0); STAGE_B(1, 1);
  VMW4; BARR;

  for (int t = 0; t < TT; ++t) {
    int bufb = (t & 1) << 16;
    #pragma unroll
    for (int f = 0; f < 4; ++f) {
      int o = bufb + aOff + f * 2048;
      af[f][0] = *(const bf16x8*)(sm + o);
      af[f][1] = *(const bf16x8*)(sm + (o ^ 64));
    }
    #pragma unroll
    for (int n = 0; n < 2; ++n) {
      int o = bufb + bOff + n * 2048;
      bf0[n][0] = *(const bf16x8*)(sm + o);
      bf0[n][1] = *(const bf16x8*)(sm + (o ^ 64));
      int o1 = bufb + bOff + 4096 + n * 2048;
      bf1[n][0] = *(const bf16x8*)(sm + o1);
      bf1[n][1] = *(const bf16x8*)(sm + (o1 ^ 64));
    }
    if (t + 1 < TT) { STAGE_A(t + 1, 0); STAGE_A(t + 1, 1); }
    LGKM0; SCHEDB;
    __builtin_amdgcn_s_setprio(1);
    QUAD(af, bf0, 0, 0);
    QUAD(af, bf1, 0, 2);
    __builtin_amdgcn_s_setprio(0);
    #pragma unroll
    for (int f = 0; f < 4; ++f) {
      int o = bufb + aOff + 8192 + f * 2048;
      af[f][0] = *(const bf16x8*)(sm + o);
      af[f][1] = *(const bf16x8*)(sm + (o ^ 64));
    }
    LGKM0; SCHEDB;
    __builtin_amdgcn_s_setprio(1);
    QUAD(af, bf1, 4, 2);
    QUAD(af, bf0, 4, 0);
    __builtin_amdgcn_s_setprio(0);
    if (t + 2 < TT) { STAGE_B(t + 2, 0); STAGE_B(t + 2, 1); }
    if (t + 2 < TT) { VMW4; } else { VMW0; }
    BARR;
  }

  #pragma unroll
  for (int n = 0; n < 4; ++n) {
    int colb = (wc * 64 + n * 16 + (lane & 15)) * 2;
    float bias = b1[e * HDIM + cb * 256 + wc * 64 + n * 16 + (lane & 15)];
    #pragma unroll
    for (int m = 0; m < 8; ++m) {
      int row = wr * 128 + m * 16 + (lane >> 4) * 4;
      #pragma unroll
      for (int j = 0; j < 4; ++j)
        *(u16*)(sm + (row + j) * 544 + colb) = f2bf(acc[m][n][j] + bias);
    }
  }
  BARR;
  #pragma unroll
  for (int p = 0; p < 16; ++p) {
    int cidx = p * 512 + tid;
    int row = cidx >> 5, cch = cidx & 31;
    u16x8 v = *(const u16x8*)(sm + row * 544 + cch * 16);
    *(u16x8*)(Hbuf + (size_t)(grb + row) * HDIM + cb * 256 + cch * 8) = v;
  }
  #undef STAGE_A
  #undef STAGE_B
}

// ============ GEMM2: 1-barrier-per-K-tile, split-K=2, dense bf16 out ============
__global__ __launch_bounds__(512, 2) void gemm2_kernel(
    const u16* __restrict__ Hbuf, const u16* __restrict__ w2t, const float* __restrict__ b2,
    const int* __restrict__ tokenlist, const int* __restrict__ cnt,
    const int* __restrict__ offsets, const float* __restrict__ combine,
    u16* __restrict__ Gout) {
  __shared__ __align__(64) unsigned char sm[139264];
  const int NB = ODIM / 256;       // 4
  const int TT = (HDIM / 2) / 64;  // 32 per split
  int nwg = NB * MBLK;
  int flat = blockIdx.y * NB + blockIdx.x;
  int q = nwg >> 3;
  int swzb = (flat & 7) * q + (flat >> 3);
  int mb = swzb / NB, cb = swzb % NB;
  int ks = blockIdx.z;
  int grb = mb * 256;
  if (grb >= offsets[NEXP]) return;
  int e = 0;
  #pragma unroll
  for (int k = 0; k < NEXP - 1; ++k) if (grb >= offsets[k + 1]) e = k + 1;
  int lr0 = grb - offsets[e];
  int cnt_e = cnt[e];
  int tid = threadIdx.x, lane = tid & 63, wave = tid >> 6;
  int wr = wave >> 2, wc = wave & 3;
  size_t ksOff = (size_t)ks * (HDIM / 2);
  u16* Gk = Gout + (size_t)ks * ROWCAP * ODIM;

  int colel = (((tid & 7) ^ ((tid >> 3) & 7)) << 3);
  const u16* pA[4]; const u16* pB[4];
  #pragma unroll
  for (int h = 0; h < 2; ++h)
    #pragma unroll
    for (int j = 0; j < 2; ++j) {
      int rowT = h * 128 + j * 64 + (tid >> 3);
      pA[h * 2 + j] = Hbuf + (size_t)(grb + rowT) * HDIM + ksOff + colel;
      pB[h * 2 + j] = w2t + ((size_t)e * ODIM + cb * 256 + rowT) * HDIM + ksOff + colel;
    }
  unsigned ldsw = wave * 1024;

  #define STAGE_A(T, H) { unsigned d = (((T) & 1) << 16) + (H) * 16384 + ldsw; \
      gload16(pA[(H)*2+0] + (T)*64, sm + d); gload16(pA[(H)*2+1] + (T)*64, sm + d + 8192); }
  #define STAGE_B(T, H) { unsigned d = (((T) & 1) << 16) + 32768 + (H) * 16384 + ldsw; \
      gload16(pB[(H)*2+0] + (T)*64, sm + d); gload16(pB[(H)*2+1] + (T)*64, sm + d + 8192); }

  int rA = lane & 15;
  int swz = (((lane >> 4) ^ (lane & 7)) << 4);
  int aOff = wr * 16384 + rA * 128 + swz;
  int bOff = 32768 + wc * 8192 + rA * 128 + swz;

  f32x4 acc[8][4];
  #pragma unroll
  for (int m = 0; m < 8; ++m)
    #pragma unroll
    for (int n = 0; n < 4; ++n) acc[m][n] = (f32x4){0.f, 0.f, 0.f, 0.f};
  bf16x8 af[4][2], bf0[2][2], bf1[2][2];

  STAGE_A(0, 0); STAGE_A(0, 1); STAGE_B(0, 0); STAGE_B(0, 1);
  CFENCE;
  STAGE_B(1, 0); STAGE_B(1, 1);
  VMW4; BARR;

  for (int t = 0; t < TT; ++t) {
    int bufb = (t & 1) << 16;
    #pragma unroll
    for (int f = 0; f < 4; ++f) {
      int o = bufb + aOff + f * 2048;
      af[f][0] = *(const bf16x8*)(sm + o);
      af[f][1] = *(const bf16x8*)(sm + (o ^ 64));
    }
    #pragma unroll
    for (int n = 0; n < 2; ++n) {
      int o = bufb + bOff + n * 2048;
      bf0[n][0] = *(const bf16x8*)(sm + o);
      bf0[n][1] = *(const bf16x8*)(sm + (o ^ 64));
      int o1 = bufb + bOff + 4096 + n * 2048;
      bf1[n][0] = *(const bf16x8*)(sm + o1);
      bf1[n][1] = *(const bf16x8*)(sm + (o1 ^ 64));
    }
    if (t + 1 < TT) { STAGE_A(t + 1, 0); STAGE_A(t + 1, 1); }
    LGKM0; SCHEDB;
    __builtin_amdgcn_s_setprio(1);
    QUAD(af, bf0, 0, 0);
    QUAD(af, bf1, 0, 2);
    __builtin_amdgcn_s_setprio(0);
    #pragma unroll
    for (int f = 0; f < 4; ++f) {
      int o = bufb + aOff + 8192 + f * 2048;
      af[f][0] = *(const bf16x8*)(sm + o);
      af[f][1] = *(const bf16x8*)(sm + (o ^ 64));
    }
    LGKM0; SCHEDB;
    __builtin_amdgcn_s_setprio(1);
    QUAD(af, bf1, 4, 2);
    QUAD(af, bf0, 4, 0);
    __builtin_amdgcn_s_setprio(0);
    if (t + 2 < TT) { STAGE_B(t + 2, 0); STAGE_B(t + 2, 1); }
    if (t + 2 < TT) { VMW4; } else { VMW0; }
    BARR;
  }

  const int* tl = tokenlist + e * NTOK;
  float bias_n[4];
  #pragma unroll
  for (int n = 0; n < 4; ++n)
    bias_n[n] = (ks == 0) ? b2[e * ODIM + cb * 256 + wc * 64 + n * 16 + (lane & 15)] : 0.f;
  #pragma unroll
  for (int m = 0; m < 8; ++m) {
    #pragma unroll
    for (int j = 0; j < 4; ++j) {
      int rr = wr * 128 + m * 16 + (lane >> 4) * 4 + j;
      int tok = tl[min(lr0 + rr, cnt_e - 1)];
      float c = combine[(size_t)tok * NEXP + e];
      #pragma unroll
      for (int n = 0; n < 4; ++n)
        *(u16*)(sm + rr * 544 + (wc * 64 + n * 16 + (lane & 15)) * 2) =
            f2bf(c * (acc[m][n][j] + bias_n[n]));
    }
  }
  BARR;
  #pragma unroll
  for (int p = 0; p < 16; ++p) {
    int cidx = p * 512 + tid;
    int row = cidx >> 5, cch = cidx & 31;
    u16x8 v = *(const u16x8*)(sm + row * 544 + cch * 16);
    *(u16x8*)(Gk + (size_t)(grb + row) * ODIM + cb * 256 + cch * 8) = v;
  }
  #undef STAGE_A
  #undef STAGE_B
}

// ---------------- LN + exact GELU in place ----------------
__global__ __launch_bounds__(256) void ln_gelu_kernel(
    u16* __restrict__ Hbuf, const float* __restrict__ g, const float* __restrict__ b,
    const int* __restrict__ offsets) {
  int r = blockIdx.x;
  if (r >= offsets[NEXP]) return;
  int e = 0;
  #pragma unroll
  for (int k = 0; k < NEXP - 1; ++k) if (r >= offsets[k + 1]) e = k + 1;
  u16* row = Hbuf + (size_t)r * HDIM;
  const float* ge = g + e * HDIM;
  const float* be = b + e * HDIM;
  int tid = threadIdx.x;
  float s = 0.f, ss = 0.f;
  short8 v[2];
  #pragma unroll
  for (int it = 0; it < 2; ++it) {
    v[it] = *(const short8*)(row + (tid + it * 256) * 8);
    #pragma unroll
    for (int j = 0; j < 8; ++j) { float f = bf2f((u16)v[it][j]); s += f; ss += f * f; }
  }
  #pragma unroll
  for (int off = 32; off; off >>= 1) { s += __shfl_xor(s, off); ss += __shfl_xor(ss, off); }
  __shared__ float rs[4], rss[4];
  int wave = tid >> 6, lane = tid & 63;
  if (lane == 0) { rs[wave] = s; rss[wave] = ss; }
  __syncthreads();
  float S = rs[0] + rs[1] + rs[2] + rs[3];
  float SS = rss[0] + rss[1] + rss[2] + rss[3];
  float mean = S * (1.f / HDIM);
  float var = SS * (1.f / HDIM) - mean * mean;
  float rstd = rsqrtf(var + 1e-5f);
  #pragma unroll
  for (int it = 0; it < 2; ++it) {
    int base = (tid + it * 256) * 8;
    f32x4 g0 = *(const f32x4*)(ge + base);
    f32x4 g1 = *(const f32x4*)(ge + base + 4);
    f32x4 b0 = *(const f32x4*)(be + base);
    f32x4 b1v = *(const f32x4*)(be + base + 4);
    u16x8 o;
    #pragma unroll
    for (int j = 0; j < 8; ++j) {
      float f = bf2f((u16)v[it][j]);
      float gg = j < 4 ? g0[j & 3] : g1[j & 3];
      float bb = j < 4 ? b0[j & 3] : b1v[j & 3];
      float y = (f - mean) * rstd * gg + bb;
      float gel = 0.5f * y * (1.f + erff(y * 0.70710678118654752f));
      o[j] = f2bf(gel);
    }
    *(u16x8*)(row + base) = o;
  }
}

// ---------------- final: gather 2 expert rows x 2 K-splits, sum, LN ----------------
__global__ __launch_bounds__(256) void final_ln_kernel(
    const u16* __restrict__ Gout, const int* __restrict__ pos,
    const int* __restrict__ offsets, const float* __restrict__ g,
    const float* __restrict__ b, float* __restrict__ out) {
  const size_t SPLIT = (size_t)ROWCAP * ODIM;
  int t = blockIdx.x;
  int tid = threadIdx.x;
  int p1 = pos[t * 2 + 0];
  int p2 = pos[t * 2 + 1];
  size_t r1 = (size_t)(offsets[p1 >> 16] + (p1 & 0xFFFF)) * ODIM + tid * 4;
  size_t r2 = (size_t)(offsets[p2 >> 16] + (p2 & 0xFFFF)) * ODIM + tid * 4;
  u16x4 a0 = *(const u16x4*)(Gout + r1);
  u16x4 a1 = *(const u16x4*)(Gout + SPLIT + r1);
  u16x4 c0 = *(const u16x4*)(Gout + r2);
  u16x4 c1 = *(const u16x4*)(Gout + SPLIT + r2);
  f32x4 v;
  #pragma unroll
  for (int j = 0; j < 4; ++j)
    v[j] = bf2f(a0[j]) + bf2f(a1[j]) + bf2f(c0[j]) + bf2f(c1[j]);
  float s = v[0] + v[1] + v[2] + v[3];
  float ss = v[0] * v[0] + v[1] * v[1] + v[2] * v[2] + v[3] * v[3];
  #pragma unroll
  for (int off = 32; off; off >>= 1) { s += __shfl_xor(s, off); ss += __shfl_xor(ss, off); }
  __shared__ float rs[4], rss[4];
  int wave = tid >> 6, lane = tid & 63;
  if (lane == 0) { rs[wave] = s; rss[wave] = ss; }
  __syncthreads();
  float S = rs[0] + rs[1] + rs[2] + rs[3];
  float SS = rss[0] + rss[1] + rss[2] + rss[3];
  float mean = S * (1.f / ODIM);
  float var = SS * (1.f / ODIM) - mean * mean;
  float rstd = rsqrtf(var + 1e-5f);
  f32x4 gv = *(const f32x4*)(g + tid * 4);
  f32x4 bv = *(const f32x4*)(b + tid * 4);
  f32x4 o;
  #pragma unroll
  for (int j = 0; j < 4; ++j) o[j] = (v[j] - mean) * rstd * gv[j] + bv[j];
  *(f32x4*)(out + (size_t)t * ODIM + tid * 4) = o;
}

extern "C" void kernel_launch(void* const* d_in, const int* in_sizes, int n_in,
                              void* d_out, int out_size, void* d_ws, size_t ws_size,
                              hipStream_t stream) {
  (void)in_sizes; (void)n_in; (void)out_size; (void)ws_size;
  const float* x    = (const float*)d_in[0];
  const float* w1   = (const float*)d_in[1];
  const float* b1   = (const float*)d_in[2];
  const float* ln1g = (const float*)d_in[3];
  const float* ln1b = (const float*)d_in[4];
  const float* w2   = (const float*)d_in[5];
  const float* b2   = (const float*)d_in[6];
  const float* wg   = (const float*)d_in[7];
  const float* bg   = (const float*)d_in[8];
  const float* outg = (const float*)d_in[9];
  const float* outb = (const float*)d_in[10];
  float* out = (float*)d_out;

  char* ws = (char*)d_ws;
  size_t off = 0;
  auto alloc = [&](size_t bytes) {
    char* p = ws + off;
    off += (bytes + 255) & ~(size_t)255;
    return p;
  };
  // Region 0: xb + w1t (dead after gemm1) aliased with Gout[2] (bf16)
  size_t xb_sz  = (size_t)NTOK * IDIM * 2;                 // 16.78 MB
  size_t w1t_sz = (size_t)NEXP * HDIM * IDIM * 2;          // 67.1 MB
  size_t gout_sz = (size_t)2 * ROWCAP * ODIM * 2;          // 75.5 MB ( < xb+w1t )
  size_t reg0 = xb_sz + w1t_sz;
  if (gout_sz > reg0) reg0 = gout_sz;
  char* base0 = (char*)alloc(reg0);
  u16* xb   = (u16*)base0;
  u16* w1t  = (u16*)(base0 + xb_sz);
  u16* Gout = (u16*)base0;

  u16* w2t       = (u16*)alloc((size_t)NEXP * ODIM * HDIM * 2);
  u16* Hbuf      = (u16*)alloc((size_t)ROWCAP * HDIM * 2);
  float* combine = (float*)alloc((size_t)NTOK * NEXP * 4);
  int* tokenlist = (int*)alloc((size_t)NEXP * NTOK * 4);
  int* pos       = (int*)alloc((size_t)NTOK * 2 * 4);
  int* sel       = (int*)alloc((size_t)NTOK * 4);
  int* cnt       = (int*)alloc(64);
  int* offsets   = (int*)alloc(64);
  float* imp_partial = (float*)alloc(GATE_BLOCKS * NEXP * 4);

  prep_kernel<<<GATE_BLOCKS + 4096, 256, 0, stream>>>(
      x, wg, bg, w1, w2, combine, imp_partial, sel, xb, w1t, w2t);
  compact_kernel<<<NEXP, 256, 0, stream>>>(sel, tokenlist, cnt, pos);
  offsets_aux_kernel<<<1, 64, 0, stream>>>(cnt, imp_partial, offsets, out + (size_t)NTOK * ODIM);
  gemm1_kernel<<<dim3(HDIM / 256, MBLK), 512, 0, stream>>>(xb, w1t, b1, tokenlist, cnt, offsets, Hbuf);
  ln_gelu_kernel<<<ROWCAP, 256, 0, stream>>>(Hbuf, ln1g, ln1b, offsets);
  gemm2_kernel<<<dim3(ODIM / 256, MBLK, 2), 512, 0, stream>>>(Hbuf, w2t, b2, tokenlist, cnt, offsets, combine, Gout);
  final_ln_kernel<<<NTOK, 256, 0, stream>>>(Gout, pos, offsets, outg, outb, out);
}

// Round 16
// 510.793 us; speedup vs baseline: 1.1102x; 1.0030x over previous
//
#include <hip/hip_runtime.h>

#define NTOK 8192
#define IDIM 1024
#define HDIM 4096
#define ODIM 1024
#define NEXP 8
#define ROWCAP 18432          // NTOK*2 + NEXP*256
#define MBLK 72               // ROWCAP / 256
#define GATE_BLOCKS 512

typedef unsigned short u16;
typedef __attribute__((ext_vector_type(8))) __bf16 bf16x8;
typedef __attribute__((ext_vector_type(8))) short short8;
typedef __attribute__((ext_vector_type(4))) float f32x4;
typedef __attribute__((ext_vector_type(4))) unsigned short u16x4;
typedef __attribute__((ext_vector_type(8))) unsigned short u16x8;

__device__ __forceinline__ u16 f2bf(float f) {
  union { float f; unsigned u; } c; c.f = f;
  unsigned u = c.u;
  return (u16)((u + 0x7fffu + ((u >> 16) & 1u)) >> 16);
}
__device__ __forceinline__ float bf2f(u16 h) {
  union { unsigned u; float f; } c; c.u = ((unsigned)h) << 16;
  return c.f;
}
__device__ __forceinline__ void gload16(const void* g, void* l) {
  __builtin_amdgcn_global_load_lds((const __attribute__((address_space(1))) unsigned*)g,
                                   (__attribute__((address_space(3))) unsigned*)l, 16, 0, 0);
}

#define BARR __builtin_amdgcn_s_barrier()
#define LGKM0 asm volatile("s_waitcnt lgkmcnt(0)" ::: "memory")
#define SCHEDB __builtin_amdgcn_sched_barrier(0)
#define VMW4 asm volatile("s_waitcnt vmcnt(4)" ::: "memory")
#define VMW0 asm volatile("s_waitcnt vmcnt(0)" ::: "memory")
#define CFENCE asm volatile("" ::: "memory")

#define QUAD(AF, BF, MB, NBQ)                                                   \
  _Pragma("unroll") for (int kk = 0; kk < 2; ++kk)                              \
  _Pragma("unroll") for (int f = 0; f < 4; ++f)                                 \
  _Pragma("unroll") for (int n = 0; n < 2; ++n)                                 \
    acc[(MB) + f][(NBQ) + n] = __builtin_amdgcn_mfma_f32_16x16x32_bf16(         \
        AF[f][kk], BF[n][kk], acc[(MB) + f][(NBQ) + n], 0, 0, 0);

// ============ prep: gating (blocks 0..511, atomic-free) + transpose (512..4607) ============
__global__ __launch_bounds__(256) void prep_kernel(
    const float* __restrict__ x, const float* __restrict__ wg, const float* __restrict__ bg,
    const float* __restrict__ w1, const float* __restrict__ w2,
    float* __restrict__ combine, float* __restrict__ imp_partial,
    int* __restrict__ sel, u16* __restrict__ xb,
    u16* __restrict__ w1t, u16* __restrict__ w2t) {
  __shared__ __align__(16) unsigned char shm[33024];
  int tid = threadIdx.x;
  if (blockIdx.x >= GATE_BLOCKS) {
    unsigned char* ldsb = shm;
    int bid = blockIdx.x - GATE_BLOCKS;
    const float* in; u16* outp; int R, C, r0, c0;
    if (bid < 2048) {
      int e = bid >> 8, t = bid & 255;
      in = w1 + (size_t)e * IDIM * HDIM; outp = w1t + (size_t)e * IDIM * HDIM;
      R = IDIM; C = HDIM;
      r0 = (t >> 5) * 128; c0 = (t & 31) * 128;
    } else {
      int b2 = bid - 2048;
      int e = b2 >> 8, t = b2 & 255;
      in = w2 + (size_t)e * HDIM * ODIM; outp = w2t + (size_t)e * HDIM * ODIM;
      R = HDIM; C = ODIM;
      r0 = (t >> 3) * 128; c0 = (t & 7) * 128;
    }
    int rr = tid >> 5, cc = (tid & 31) * 4;
    #pragma unroll
    for (int it = 0; it < 16; ++it) {
      int r = it * 8 + rr;
      f32x4 v = *(const f32x4*)(in + (size_t)(r0 + r) * C + c0 + cc);
      u16x4 o;
      #pragma unroll
      for (int j = 0; j < 4; ++j) o[j] = f2bf(v[j]);
      unsigned a = ((unsigned)(r * 256 + cc * 2)) ^ ((((unsigned)r >> 3) & 7u) << 4);
      *(u16x4*)(ldsb + a) = o;
    }
    __syncthreads();
    int rc = tid & 15, cg = tid >> 4;
    #pragma unroll
    for (int i = 0; i < 8; ++i) {
      int c = cg + i * 16;
      u16x8 o;
      #pragma unroll
      for (int k = 0; k < 8; ++k) {
        int r = rc * 8 + k;
        unsigned a = ((unsigned)(r * 256 + c * 2)) ^ ((((unsigned)r >> 3) & 7u) << 4);
        o[k] = *(const u16*)(ldsb + a);
      }
      *(u16x8*)(outp + (size_t)(c0 + c) * R + r0 + rc * 8) = o;
    }
    return;
  }
  float* wgs3 = (float*)shm;
  float (*impw)[NEXP] = (float(*)[NEXP])(shm + 32768);
  for (int d = tid; d < IDIM * NEXP; d += 256)
    wgs3[d] = wg[(d & 1023) * 8 + (d >> 10)];
  __syncthreads();
  int wave = tid >> 6, lane = tid & 63;
  float impacc[NEXP];
  #pragma unroll
  for (int e = 0; e < NEXP; ++e) impacc[e] = 0.f;

  #pragma unroll
  for (int it = 0; it < 4; ++it) {
    int t = blockIdx.x * 16 + wave * 4 + it;
    const float* xr = x + (size_t)t * IDIM;
    u16* xbw = xb + (size_t)t * IDIM;
    float s[NEXP];
    #pragma unroll
    for (int e = 0; e < NEXP; ++e) s[e] = 0.f;
    #pragma unroll
    for (int ii = 0; ii < 4; ++ii) {
      int base = ii * 256 + lane * 4;
      f32x4 xv = *(const f32x4*)(xr + base);
      u16x4 o;
      #pragma unroll
      for (int j = 0; j < 4; ++j) o[j] = f2bf(xv[j]);
      *(u16x4*)(xbw + base) = o;
      const float* wp = wgs3 + (size_t)(ii * 64 + lane) * 4;
      #pragma unroll
      for (int e = 0; e < NEXP; ++e) {
        f32x4 wv = *(const f32x4*)(wp + e * 1024);
        s[e] = fmaf(xv[0], wv[0], s[e]);
        s[e] = fmaf(xv[1], wv[1], s[e]);
        s[e] = fmaf(xv[2], wv[2], s[e]);
        s[e] = fmaf(xv[3], wv[3], s[e]);
      }
    }
    #pragma unroll
    for (int e = 0; e < NEXP; ++e) {
      #pragma unroll
      for (int off = 32; off; off >>= 1) s[e] += __shfl_xor(s[e], off);
    }
    if (lane == 0) {
      #pragma unroll
      for (int e = 0; e < NEXP; ++e) s[e] += bg[e];
      int i1 = 0; float v1 = s[0];
      #pragma unroll
      for (int e = 1; e < NEXP; ++e) if (s[e] > v1) { v1 = s[e]; i1 = e; }
      int i2 = -1; float v2 = -1e30f;
      #pragma unroll
      for (int e = 0; e < NEXP; ++e) if (e != i1 && s[e] > v2) { v2 = s[e]; i2 = e; }
      float p[NEXP], sum = 0.f;
      #pragma unroll
      for (int e = 0; e < NEXP; ++e) { p[e] = expf(s[e] - v1); sum += p[e]; }
      float inv = 1.f / sum;
      #pragma unroll
      for (int e = 0; e < NEXP; ++e) { p[e] *= inv; impacc[e] += p[e]; }
      float c1 = 1.f / (1.f + expf(v2 - v1));
      float c2 = 1.f - c1;
      #pragma unroll
      for (int e = 0; e < NEXP; ++e) combine[(size_t)t * NEXP + e] = 0.f;
      combine[(size_t)t * NEXP + i1] = c1;
      combine[(size_t)t * NEXP + i2] = c2;
      sel[t] = i1 | (i2 << 4);
    }
  }
  if (lane == 0) {
    #pragma unroll
    for (int e = 0; e < NEXP; ++e) impw[wave][e] = impacc[e];
  }
  __syncthreads();
  if (tid == 0) {
    #pragma unroll
    for (int e = 0; e < NEXP; ++e)
      imp_partial[blockIdx.x * NEXP + e] = impw[0][e] + impw[1][e] + impw[2][e] + impw[3][e];
  }
}

// ---------------- compact: 8 blocks (one per expert); token-ordered, deterministic ----------------
__global__ __launch_bounds__(256) void compact_kernel(
    const int* __restrict__ sel, int* __restrict__ tokenlist,
    int* __restrict__ cnt, int* __restrict__ pos) {
  __shared__ int warpsum[4];
  int e = blockIdx.x;
  int tid = threadIdx.x, lane = tid & 63, wave = tid >> 6;
  int base = 0;
  for (int chunk = 0; chunk < NTOK; chunk += 256) {
    int t = chunk + tid;
    int s = sel[t];
    int i1 = s & 15, i2 = s >> 4;
    bool m2 = (i2 == e);
    bool m = (i1 == e) || m2;
    unsigned long long bal = __ballot(m);
    int rank = __popcll(bal & ((1ull << lane) - 1ull));
    if (lane == 0) warpsum[wave] = __popcll(bal);
    __syncthreads();
    int woff = 0;
    #pragma unroll
    for (int w = 0; w < 4; ++w) if (w < wave) woff += warpsum[w];
    int total = warpsum[0] + warpsum[1] + warpsum[2] + warpsum[3];
    if (m) {
      int slot = base + woff + rank;
      tokenlist[e * NTOK + slot] = t;
      pos[t * 2 + (m2 ? 1 : 0)] = (e << 16) | slot;
    }
    base += total;
    __syncthreads();
  }
  if (tid == 0) cnt[e] = base;
}

// ---------------- offsets (pad to 256) + aux loss ----------------
__global__ __launch_bounds__(64) void offsets_aux_kernel(
    const int* __restrict__ cnt, const float* __restrict__ imp_partial,
    int* __restrict__ offsets, float* __restrict__ aux_out) {
  __shared__ float imp[NEXP];
  int tid = threadIdx.x;
  if (tid < NEXP) {
    float v = 0.f;
    for (int b = 0; b < GATE_BLOCKS; ++b) v += imp_partial[b * NEXP + tid];
    imp[tid] = v;
  }
  __syncthreads();
  if (tid == 0) {
    int off = 0;
    for (int e = 0; e < NEXP; ++e) { offsets[e] = off; off += (cnt[e] + 255) & ~255; }
    offsets[NEXP] = off;
    double im = 0.0;
    for (int e = 0; e < NEXP; ++e) im += imp[e];
    im /= NEXP;
    double iv = 0.0;
    for (int e = 0; e < NEXP; ++e) { double d = (double)imp[e] - im; iv += d * d; }
    iv /= (NEXP - 1);
    double il = sqrt(iv) / (im + 1e-6); il = il * il;
    double lm = 0.0;
    for (int e = 0; e < NEXP; ++e) lm += cnt[e];
    lm /= (double)NEXP * NTOK;
    double lv = 0.0;
    for (int e = 0; e < NEXP; ++e) { double d = (double)cnt[e] / NTOK - lm; lv += d * d; }
    lv /= (NEXP - 1);
    double ll = sqrt(lv) / (lm + 1e-6); ll = ll * ll;
    aux_out[0] = (float)(il + ll);
  }
}

// ============ GEMM1: 1-barrier-per-K-tile (R14-verified) ============
__global__ __launch_bounds__(512, 2) void gemm1_kernel(
    const u16* __restrict__ xb, const u16* __restrict__ w1t, const float* __restrict__ b1,
    const int* __restrict__ tokenlist, const int* __restrict__ cnt,
    const int* __restrict__ offsets, u16* __restrict__ Hbuf) {
  __shared__ __align__(64) unsigned char sm[139264];
  const int NB = HDIM / 256;       // 16
  const int TT = IDIM / 64;        // 16
  int nwg = NB * MBLK;
  int flat = blockIdx.y * NB + blockIdx.x;
  int q = nwg >> 3;
  int swzb = (flat & 7) * q + (flat >> 3);
  int mb = swzb / NB, cb = swzb % NB;
  int grb = mb * 256;
  if (grb >= offsets[NEXP]) return;
  int e = 0;
  #pragma unroll
  for (int k = 0; k < NEXP - 1; ++k) if (grb >= offsets[k + 1]) e = k + 1;
  int lr0 = grb - offsets[e];
  int cnt_e = cnt[e];
  int tid = threadIdx.x, lane = tid & 63, wave = tid >> 6;
  int wr = wave >> 2, wc = wave & 3;

  const int* tl = tokenlist + e * NTOK;
  int colel = (((tid & 7) ^ ((tid >> 3) & 7)) << 3);
  const u16* pA[4]; const u16* pB[4];
  #pragma unroll
  for (int h = 0; h < 2; ++h)
    #pragma unroll
    for (int j = 0; j < 2; ++j) {
      int rowT = h * 128 + j * 64 + (tid >> 3);
      int tok = tl[min(lr0 + rowT, cnt_e - 1)];
      pA[h * 2 + j] = xb + (size_t)tok * IDIM + colel;
      pB[h * 2 + j] = w1t + ((size_t)e * HDIM + cb * 256 + rowT) * IDIM + colel;
    }
  unsigned ldsw = wave * 1024;

  #define STAGE_A(T, H) { unsigned d = (((T) & 1) << 16) + (H) * 16384 + ldsw; \
      gload16(pA[(H)*2+0] + (T)*64, sm + d); gload16(pA[(H)*2+1] + (T)*64, sm + d + 8192); }
  #define STAGE_B(T, H) { unsigned d = (((T) & 1) << 16) + 32768 + (H) * 16384 + ldsw; \
      gload16(pB[(H)*2+0] + (T)*64, sm + d); gload16(pB[(H)*2+1] + (T)*64, sm + d + 8192); }

  int rA = lane & 15;
  int swz = (((lane >> 4) ^ (lane & 7)) << 4);
  int aOff = wr * 16384 + rA * 128 + swz;
  int bOff = 32768 + wc * 8192 + rA * 128 + swz;

  f32x4 acc[8][4];
  #pragma unroll
  for (int m = 0; m < 8; ++m)
    #pragma unroll
    for (int n = 0; n < 4; ++n) acc[m][n] = (f32x4){0.f, 0.f, 0.f, 0.f};
  bf16x8 af[4][2], bf0[2][2], bf1[2][2];

  STAGE_A(0, 0); STAGE_A(0, 1); STAGE_B(0, 0); STAGE_B(0, 1);
  CFENCE;
  STAGE_B(1, 0); STAGE_B(1, 1);
  VMW4; BARR;

  for (int t = 0; t < TT; ++t) {
    int bufb = (t & 1) << 16;
    #pragma unroll
    for (int f = 0; f < 4; ++f) {
      int o = bufb + aOff + f * 2048;
      af[f][0] = *(const bf16x8*)(sm + o);
      af[f][1] = *(const bf16x8*)(sm + (o ^ 64));
    }
    #pragma unroll
    for (int n = 0; n < 2; ++n) {
      int o = bufb + bOff + n * 2048;
      bf0[n][0] = *(const bf16x8*)(sm + o);
      bf0[n][1] = *(const bf16x8*)(sm + (o ^ 64));
      int o1 = bufb + bOff + 4096 + n * 2048;
      bf1[n][0] = *(const bf16x8*)(sm + o1);
      bf1[n][1] = *(const bf16x8*)(sm + (o1 ^ 64));
    }
    if (t + 1 < TT) { STAGE_A(t + 1, 0); STAGE_A(t + 1, 1); }
    LGKM0; SCHEDB;
    __builtin_amdgcn_s_setprio(1);
    QUAD(af, bf0, 0, 0);
    QUAD(af, bf1, 0, 2);
    __builtin_amdgcn_s_setprio(0);
    #pragma unroll
    for (int f = 0; f < 4; ++f) {
      int o = bufb + aOff + 8192 + f * 2048;
      af[f][0] = *(const bf16x8*)(sm + o);
      af[f][1] = *(const bf16x8*)(sm + (o ^ 64));
    }
    LGKM0; SCHEDB;
    __builtin_amdgcn_s_setprio(1);
    QUAD(af, bf1, 4, 2);
    QUAD(af, bf0, 4, 0);
    __builtin_amdgcn_s_setprio(0);
    if (t + 2 < TT) { STAGE_B(t + 2, 0); STAGE_B(t + 2, 1); }
    if (t + 2 < TT) { VMW4; } else { VMW0; }
    BARR;
  }

  #pragma unroll
  for (int n = 0; n < 4; ++n) {
    int colb = (wc * 64 + n * 16 + (lane & 15)) * 2;
    float bias = b1[e * HDIM + cb * 256 + wc * 64 + n * 16 + (lane & 15)];
    #pragma unroll
    for (int m = 0; m < 8; ++m) {
      int row = wr * 128 + m * 16 + (lane >> 4) * 4;
      #pragma unroll
      for (int j = 0; j < 4; ++j)
        *(u16*)(sm + (row + j) * 544 + colb) = f2bf(acc[m][n][j] + bias);
    }
  }
  BARR;
  #pragma unroll
  for (int p = 0; p < 16; ++p) {
    int cidx = p * 512 + tid;
    int row = cidx >> 5, cch = cidx & 31;
    u16x8 v = *(const u16x8*)(sm + row * 544 + cch * 16);
    *(u16x8*)(Hbuf + (size_t)(grb + row) * HDIM + cb * 256 + cch * 8) = v;
  }
  #undef STAGE_A
  #undef STAGE_B
}

// ============ GEMM2: 1-barrier-per-K-tile, split-K=2, dense bf16 out (R14-verified) ============
__global__ __launch_bounds__(512, 2) void gemm2_kernel(
    const u16* __restrict__ Hbuf, const u16* __restrict__ w2t, const float* __restrict__ b2,
    const int* __restrict__ tokenlist, const int* __restrict__ cnt,
    const int* __restrict__ offsets, const float* __restrict__ combine,
    u16* __restrict__ Gout) {
  __shared__ __align__(64) unsigned char sm[139264];
  const int NB = ODIM / 256;       // 4
  const int TT = (HDIM / 2) / 64;  // 32 per split
  int nwg = NB * MBLK;
  int flat = blockIdx.y * NB + blockIdx.x;
  int q = nwg >> 3;
  int swzb = (flat & 7) * q + (flat >> 3);
  int mb = swzb / NB, cb = swzb % NB;
  int ks = blockIdx.z;
  int grb = mb * 256;
  if (grb >= offsets[NEXP]) return;
  int e = 0;
  #pragma unroll
  for (int k = 0; k < NEXP - 1; ++k) if (grb >= offsets[k + 1]) e = k + 1;
  int lr0 = grb - offsets[e];
  int cnt_e = cnt[e];
  int tid = threadIdx.x, lane = tid & 63, wave = tid >> 6;
  int wr = wave >> 2, wc = wave & 3;
  size_t ksOff = (size_t)ks * (HDIM / 2);
  u16* Gk = Gout + (size_t)ks * ROWCAP * ODIM;

  int colel = (((tid & 7) ^ ((tid >> 3) & 7)) << 3);
  const u16* pA[4]; const u16* pB[4];
  #pragma unroll
  for (int h = 0; h < 2; ++h)
    #pragma unroll
    for (int j = 0; j < 2; ++j) {
      int rowT = h * 128 + j * 64 + (tid >> 3);
      pA[h * 2 + j] = Hbuf + (size_t)(grb + rowT) * HDIM + ksOff + colel;
      pB[h * 2 + j] = w2t + ((size_t)e * ODIM + cb * 256 + rowT) * HDIM + ksOff + colel;
    }
  unsigned ldsw = wave * 1024;

  #define STAGE_A(T, H) { unsigned d = (((T) & 1) << 16) + (H) * 16384 + ldsw; \
      gload16(pA[(H)*2+0] + (T)*64, sm + d); gload16(pA[(H)*2+1] + (T)*64, sm + d + 8192); }
  #define STAGE_B(T, H) { unsigned d = (((T) & 1) << 16) + 32768 + (H) * 16384 + ldsw; \
      gload16(pB[(H)*2+0] + (T)*64, sm + d); gload16(pB[(H)*2+1] + (T)*64, sm + d + 8192); }

  int rA = lane & 15;
  int swz = (((lane >> 4) ^ (lane & 7)) << 4);
  int aOff = wr * 16384 + rA * 128 + swz;
  int bOff = 32768 + wc * 8192 + rA * 128 + swz;

  f32x4 acc[8][4];
  #pragma unroll
  for (int m = 0; m < 8; ++m)
    #pragma unroll
    for (int n = 0; n < 4; ++n) acc[m][n] = (f32x4){0.f, 0.f, 0.f, 0.f};
  bf16x8 af[4][2], bf0[2][2], bf1[2][2];

  STAGE_A(0, 0); STAGE_A(0, 1); STAGE_B(0, 0); STAGE_B(0, 1);
  CFENCE;
  STAGE_B(1, 0); STAGE_B(1, 1);
  VMW4; BARR;

  for (int t = 0; t < TT; ++t) {
    int bufb = (t & 1) << 16;
    #pragma unroll
    for (int f = 0; f < 4; ++f) {
      int o = bufb + aOff + f * 2048;
      af[f][0] = *(const bf16x8*)(sm + o);
      af[f][1] = *(const bf16x8*)(sm + (o ^ 64));
    }
    #pragma unroll
    for (int n = 0; n < 2; ++n) {
      int o = bufb + bOff + n * 2048;
      bf0[n][0] = *(const bf16x8*)(sm + o);
      bf0[n][1] = *(const bf16x8*)(sm + (o ^ 64));
      int o1 = bufb + bOff + 4096 + n * 2048;
      bf1[n][0] = *(const bf16x8*)(sm + o1);
      bf1[n][1] = *(const bf16x8*)(sm + (o1 ^ 64));
    }
    if (t + 1 < TT) { STAGE_A(t + 1, 0); STAGE_A(t + 1, 1); }
    LGKM0; SCHEDB;
    __builtin_amdgcn_s_setprio(1);
    QUAD(af, bf0, 0, 0);
    QUAD(af, bf1, 0, 2);
    __builtin_amdgcn_s_setprio(0);
    #pragma unroll
    for (int f = 0; f < 4; ++f) {
      int o = bufb + aOff + 8192 + f * 2048;
      af[f][0] = *(const bf16x8*)(sm + o);
      af[f][1] = *(const bf16x8*)(sm + (o ^ 64));
    }
    LGKM0; SCHEDB;
    __builtin_amdgcn_s_setprio(1);
    QUAD(af, bf1, 4, 2);
    QUAD(af, bf0, 4, 0);
    __builtin_amdgcn_s_setprio(0);
    if (t + 2 < TT) { STAGE_B(t + 2, 0); STAGE_B(t + 2, 1); }
    if (t + 2 < TT) { VMW4; } else { VMW0; }
    BARR;
  }

  const int* tl = tokenlist + e * NTOK;
  float bias_n[4];
  #pragma unroll
  for (int n = 0; n < 4; ++n)
    bias_n[n] = (ks == 0) ? b2[e * ODIM + cb * 256 + wc * 64 + n * 16 + (lane & 15)] : 0.f;
  #pragma unroll
  for (int m = 0; m < 8; ++m) {
    #pragma unroll
    for (int j = 0; j < 4; ++j) {
      int rr = wr * 128 + m * 16 + (lane >> 4) * 4 + j;
      int tok = tl[min(lr0 + rr, cnt_e - 1)];
      float c = combine[(size_t)tok * NEXP + e];
      #pragma unroll
      for (int n = 0; n < 4; ++n)
        *(u16*)(sm + rr * 544 + (wc * 64 + n * 16 + (lane & 15)) * 2) =
            f2bf(c * (acc[m][n][j] + bias_n[n]));
    }
  }
  BARR;
  #pragma unroll
  for (int p = 0; p < 16; ++p) {
    int cidx = p * 512 + tid;
    int row = cidx >> 5, cch = cidx & 31;
    u16x8 v = *(const u16x8*)(sm + row * 544 + cch * 16);
    *(u16x8*)(Gk + (size_t)(grb + row) * ODIM + cb * 256 + cch * 8) = v;
  }
  #undef STAGE_A
  #undef STAGE_B
}

// ---------------- LN + exact GELU in place ----------------
__global__ __launch_bounds__(256) void ln_gelu_kernel(
    u16* __restrict__ Hbuf, const float* __restrict__ g, const float* __restrict__ b,
    const int* __restrict__ offsets) {
  int r = blockIdx.x;
  if (r >= offsets[NEXP]) return;
  int e = 0;
  #pragma unroll
  for (int k = 0; k < NEXP - 1; ++k) if (r >= offsets[k + 1]) e = k + 1;
  u16* row = Hbuf + (size_t)r * HDIM;
  const float* ge = g + e * HDIM;
  const float* be = b + e * HDIM;
  int tid = threadIdx.x;
  float s = 0.f, ss = 0.f;
  short8 v[2];
  #pragma unroll
  for (int it = 0; it < 2; ++it) {
    v[it] = *(const short8*)(row + (tid + it * 256) * 8);
    #pragma unroll
    for (int j = 0; j < 8; ++j) { float f = bf2f((u16)v[it][j]); s += f; ss += f * f; }
  }
  #pragma unroll
  for (int off = 32; off; off >>= 1) { s += __shfl_xor(s, off); ss += __shfl_xor(ss, off); }
  __shared__ float rs[4], rss[4];
  int wave = tid >> 6, lane = tid & 63;
  if (lane == 0) { rs[wave] = s; rss[wave] = ss; }
  __syncthreads();
  float S = rs[0] + rs[1] + rs[2] + rs[3];
  float SS = rss[0] + rss[1] + rss[2] + rss[3];
  float mean = S * (1.f / HDIM);
  float var = SS * (1.f / HDIM) - mean * mean;
  float rstd = rsqrtf(var + 1e-5f);
  #pragma unroll
  for (int it = 0; it < 2; ++it) {
    int base = (tid + it * 256) * 8;
    f32x4 g0 = *(const f32x4*)(ge + base);
    f32x4 g1 = *(const f32x4*)(ge + base + 4);
    f32x4 b0 = *(const f32x4*)(be + base);
    f32x4 b1v = *(const f32x4*)(be + base + 4);
    u16x8 o;
    #pragma unroll
    for (int j = 0; j < 8; ++j) {
      float f = bf2f((u16)v[it][j]);
      float gg = j < 4 ? g0[j & 3] : g1[j & 3];
      float bb = j < 4 ? b0[j & 3] : b1v[j & 3];
      float y = (f - mean) * rstd * gg + bb;
      float gel = 0.5f * y * (1.f + erff(y * 0.70710678118654752f));
      o[j] = f2bf(gel);
    }
    *(u16x8*)(row + base) = o;
  }
}

// ---------------- final: gather 2 expert rows x 2 K-splits, sum, LN ----------------
__global__ __launch_bounds__(256) void final_ln_kernel(
    const u16* __restrict__ Gout, const int* __restrict__ pos,
    const int* __restrict__ offsets, const float* __restrict__ g,
    const float* __restrict__ b, float* __restrict__ out) {
  const size_t SPLIT = (size_t)ROWCAP * ODIM;
  int t = blockIdx.x;
  int tid = threadIdx.x;
  int p1 = pos[t * 2 + 0];
  int p2 = pos[t * 2 + 1];
  size_t r1 = (size_t)(offsets[p1 >> 16] + (p1 & 0xFFFF)) * ODIM + tid * 4;
  size_t r2 = (size_t)(offsets[p2 >> 16] + (p2 & 0xFFFF)) * ODIM + tid * 4;
  u16x4 a0 = *(const u16x4*)(Gout + r1);
  u16x4 a1 = *(const u16x4*)(Gout + SPLIT + r1);
  u16x4 c0 = *(const u16x4*)(Gout + r2);
  u16x4 c1 = *(const u16x4*)(Gout + SPLIT + r2);
  f32x4 v;
  #pragma unroll
  for (int j = 0; j < 4; ++j)
    v[j] = bf2f(a0[j]) + bf2f(a1[j]) + bf2f(c0[j]) + bf2f(c1[j]);
  float s = v[0] + v[1] + v[2] + v[3];
  float ss = v[0] * v[0] + v[1] * v[1] + v[2] * v[2] + v[3] * v[3];
  #pragma unroll
  for (int off = 32; off; off >>= 1) { s += __shfl_xor(s, off); ss += __shfl_xor(ss, off); }
  __shared__ float rs[4], rss[4];
  int wave = tid >> 6, lane = tid & 63;
  if (lane == 0) { rs[wave] = s; rss[wave] = ss; }
  __syncthreads();
  float S = rs[0] + rs[1] + rs[2] + rs[3];
  float SS = rss[0] + rss[1] + rss[2] + rss[3];
  float mean = S * (1.f / ODIM);
  float var = SS * (1.f / ODIM) - mean * mean;
  float rstd = rsqrtf(var + 1e-5f);
  f32x4 gv = *(const f32x4*)(g + tid * 4);
  f32x4 bv = *(const f32x4*)(b + tid * 4);
  f32x4 o;
  #pragma unroll
  for (int j = 0; j < 4; ++j) o[j] = (v[j] - mean) * rstd * gv[j] + bv[j];
  *(f32x4*)(out + (size_t)t * ODIM + tid * 4) = o;
}

extern "C" void kernel_launch(void* const* d_in, const int* in_sizes, int n_in,
                              void* d_out, int out_size, void* d_ws, size_t ws_size,
                              hipStream_t stream) {
  (void)in_sizes; (void)n_in; (void)out_size; (void)ws_size;
  const float* x    = (const float*)d_in[0];
  const float* w1   = (const float*)d_in[1];
  const float* b1   = (const float*)d_in[2];
  const float* ln1g = (const float*)d_in[3];
  const float* ln1b = (const float*)d_in[4];
  const float* w2   = (const float*)d_in[5];
  const float* b2   = (const float*)d_in[6];
  const float* wg   = (const float*)d_in[7];
  const float* bg   = (const float*)d_in[8];
  const float* outg = (const float*)d_in[9];
  const float* outb = (const float*)d_in[10];
  float* out = (float*)d_out;

  char* ws = (char*)d_ws;
  size_t off = 0;
  auto alloc = [&](size_t bytes) {
    char* p = ws + off;
    off += (bytes + 255) & ~(size_t)255;
    return p;
  };
  // Region 0: xb + w1t (dead after gemm1) aliased with Gout[2] (bf16)
  size_t xb_sz  = (size_t)NTOK * IDIM * 2;                 // 16.78 MB
  size_t w1t_sz = (size_t)NEXP * HDIM * IDIM * 2;          // 67.1 MB
  size_t gout_sz = (size_t)2 * ROWCAP * ODIM * 2;          // 75.5 MB ( < xb+w1t )
  size_t reg0 = xb_sz + w1t_sz;
  if (gout_sz > reg0) reg0 = gout_sz;
  char* base0 = (char*)alloc(reg0);
  u16* xb   = (u16*)base0;
  u16* w1t  = (u16*)(base0 + xb_sz);
  u16* Gout = (u16*)base0;

  u16* w2t       = (u16*)alloc((size_t)NEXP * ODIM * HDIM * 2);
  u16* Hbuf      = (u16*)alloc((size_t)ROWCAP * HDIM * 2);
  float* combine = (float*)alloc((size_t)NTOK * NEXP * 4);
  int* tokenlist = (int*)alloc((size_t)NEXP * NTOK * 4);
  int* pos       = (int*)alloc((size_t)NTOK * 2 * 4);
  int* sel       = (int*)alloc((size_t)NTOK * 4);
  int* cnt       = (int*)alloc(64);
  int* offsets   = (int*)alloc(64);
  float* imp_partial = (float*)alloc(GATE_BLOCKS * NEXP * 4);

  prep_kernel<<<GATE_BLOCKS + 4096, 256, 0, stream>>>(
      x, wg, bg, w1, w2, combine, imp_partial, sel, xb, w1t, w2t);
  compact_kernel<<<NEXP, 256, 0, stream>>>(sel, tokenlist, cnt, pos);
  offsets_aux_kernel<<<1, 64, 0, stream>>>(cnt, imp_partial, offsets, out + (size_t)NTOK * ODIM);
  gemm1_kernel<<<dim3(HDIM / 256, MBLK), 512, 0, stream>>>(xb, w1t, b1, tokenlist, cnt, offsets, Hbuf);
  ln_gelu_kernel<<<ROWCAP, 256, 0, stream>>>(Hbuf, ln1g, ln1b, offsets);
  gemm2_kernel<<<dim3(ODIM / 256, MBLK, 2), 512, 0, stream>>>(Hbuf, w2t, b2, tokenlist, cnt, offsets, combine, Gout);
  final_ln_kernel<<<NTOK, 256, 0, stream>>>(Gout, pos, offsets, outg, outb, out);
}